// Round 7
// baseline (233.351 us; speedup 1.0000x reference)
//
#include <hip/hip_runtime.h>
#include <math.h>

#define N_S 8192
#define N_T 4096
#define DIN 128
#define NF  64
#define SPL0 8
#define SPL1 4

typedef __attribute__((ext_vector_type(8))) short short8;
typedef __attribute__((ext_vector_type(4))) float f32x4;
typedef unsigned long long u64;
typedef unsigned int u32;

__device__ __forceinline__ unsigned short f2bf(float x){
  unsigned u = __float_as_uint(x);
  unsigned r = (u + 0x7fffu + ((u >> 16) & 1u)) >> 16;
  return (unsigned short)r;
}

// fragment-major bf16 layout: B-frag for MFMA reads 1KB contiguous per wave
__device__ __forceinline__ size_t xt2_idx(int f, int k){
  return ((size_t)(k >> 5))*2048 + (size_t)((f >> 4)*512 + ((k >> 3) & 3)*128 + (f & 15)*8 + (k & 7));
}

// ---------------- K1: fused {compact A -> bitmasks} + {projections} + {counter zeroing}
__global__ __launch_bounds__(256) void k1_fused(
    const int* __restrict__ A,
    u64* __restrict__ RBt,       // [N_S/64][N_T]  bits of row i over j, chunk-major
    u64* __restrict__ CBt,       // [N_T/64][N_S]  bits of col j over i, chunk-major
    const float* __restrict__ hs, const float* __restrict__ ht,
    const float* __restrict__ Ws, const float* __restrict__ Wt,
    const float* __restrict__ a1,
    unsigned short* __restrict__ XT2s, unsigned short* __restrict__ XT2t,
    float* __restrict__ EFs, float* __restrict__ EFt,
    int* __restrict__ cnt)
{
  __shared__ __align__(16) float smem[DIN*NF + 4*DIN];
  int bx = blockIdx.x;
  int t = threadIdx.x;
  if (bx == 0 && t < 192) cnt[t] = 0;    // split-K completion counters, re-zeroed every call
  if (bx < 2048) {
    // ---- compact 64x256 tile ----
    unsigned* T4 = (unsigned*)smem;      // 16*65 words
    int i0 = (bx & 63) * 64;
    int j0 = (bx >> 6) * 256;
    int w = t >> 6, l = t & 63;
    int4 v[16];
    #pragma unroll
    for (int it = 0; it < 16; ++it)
      v[it] = *(const int4*)&A[(size_t)(i0 + w*16 + it)*N_S + j0 + 4*l];
    #pragma unroll
    for (int rg = 0; rg < 4; ++rg) {
      unsigned p = 0;
      #pragma unroll
      for (int rr = 0; rr < 4; ++rr) {
        int4 m = v[rg*4 + rr];
        unsigned nib = (m.x > 0 ? 1u : 0u) | (m.y > 0 ? 2u : 0u)
                     | (m.z > 0 ? 4u : 0u) | (m.w > 0 ? 8u : 0u);
        p |= nib << (8*rr);
      }
      T4[(w*4 + rg)*65 + l] = p;
    }
    __syncthreads();
    {
      int r = t & 63, g = t >> 6;
      u64 bits = 0;
      #pragma unroll
      for (int i = 0; i < 16; ++i) {
        unsigned word = T4[(r >> 2)*65 + g*16 + i];
        unsigned nib = (word >> (8*(r & 3))) & 0xFu;
        bits |= (u64)nib << (4*i);
      }
      RBt[(size_t)((j0 >> 6) + g)*N_T + i0 + r] = bits;
    }
    {
      int c = t;
      u64 bits = 0;
      #pragma unroll
      for (int rg = 0; rg < 16; ++rg) {
        unsigned word = T4[rg*65 + (c >> 2)];
        unsigned x = (word >> (c & 3)) & 0x01010101u;
        unsigned nib = (x * 0x01020408u) >> 24;
        bits |= (u64)(nib & 0xFu) << (4*rg);
      }
      CBt[(size_t)(i0 >> 6)*N_S + j0 + c] = bits;
    }
  } else {
    // ---- proj: 4 rows -> XT2 + EF tables {exp(p), exp(0.1p)} ----
    int b = bx - 2048;
    float* Wl = smem;
    float* hrow = smem + DIN*NF;
    bool is_s = b < (N_S/4);
    const float* h; const float* W; const float* av;
    unsigned short* XT; float* EFd; int r0;
    if (is_s) { r0 = b*4;           h = hs; W = Ws; av = a1 + 64; XT = XT2s; EFd = EFs; }
    else      { r0 = (b - N_S/4)*4; h = ht; W = Wt; av = a1;      XT = XT2t; EFd = EFt; }
    for (int i = t; i < DIN*NF; i += 256) Wl[i] = W[i];
    for (int i = t; i < 4*DIN;  i += 256) hrow[i] = h[(size_t)r0*DIN + i];
    __syncthreads();
    int f = t & 63, sr = t >> 6;
    float acc = 0.f;
    #pragma unroll 8
    for (int k = 0; k < DIN; ++k) acc += hrow[sr*DIN + k] * Wl[k*NF + f];
    int r = r0 + sr;
    XT[xt2_idx(f, r)] = f2bf(acc);
    float p = acc * av[f];
    #pragma unroll
    for (int o = 32; o > 0; o >>= 1) p += __shfl_xor(p, o, 64);
    if (f == 0) { EFd[2*r] = __expf(p); EFd[2*r + 1] = __expf(0.1f*p); }
  }
}

// ---------------- K2: fused both-direction masked aggregation + last-block finalize.
// w(u,k) = bit(u,k) * max(Eu*Ek, Fu*Fk)  (= exp(lrelu(bu+vk)), exp monotone; no shift needed)
template<int DIR>
__device__ __forceinline__ void agg_body(
    int rb, int split,
    const u64* __restrict__ MBt,
    const float* __restrict__ EFu, const float* __restrict__ EFk,
    const unsigned short* __restrict__ XT2,
    float* __restrict__ accP,   // [SPL][NU][NF]
    float* __restrict__ sumP,   // [SPL][NU]
    int* __restrict__ cnt,      // per-(dir,rb) completion counter
    const float* __restrict__ bias,
    float* __restrict__ outB)
{
  constexpr int NK = (DIR == 0) ? N_S : N_T;
  constexpr int NU = (DIR == 0) ? N_T : N_S;
  constexpr int SPL = (DIR == 0) ? SPL0 : SPL1;
  constexpr int KCH = NK / SPL;
  int t = threadIdx.x;
  int wave = t >> 6, l = t & 63;
  int row16 = l & 15, grp = l >> 4;
  int u = rb*64 + wave*16 + row16;
  float2 ef = *(const float2*)&EFu[2*u];
  float Eu = ef.x, Fu = ef.y;
  f32x4 acc[4];
  #pragma unroll
  for (int q = 0; q < 4; ++q) { acc[q][0]=0.f; acc[q][1]=0.f; acc[q][2]=0.f; acc[q][3]=0.f; }
  f32x4 accs; accs[0]=0.f; accs[1]=0.f; accs[2]=0.f; accs[3]=0.f;
  short8 bones;
  #pragma unroll
  for (int j = 0; j < 8; ++j) bones[j] = (short)0x3F80;   // bf16(1.0)
  int kc0 = split * KCH;

  #pragma unroll 2
  for (int k0 = kc0; k0 < kc0 + KCH; k0 += 64) {
    u64 mb = MBt[(size_t)(k0 >> 6)*NU + u];
    u32 mlo = (u32)mb, mhi = (u32)(mb >> 32);
    short8 af01[2];
    #pragma unroll
    for (int h = 0; h < 2; ++h) {
      int kb = k0 + 32*h + grp*8;
      float4 p0 = *(const float4*)&EFk[2*kb];
      float4 p1 = *(const float4*)&EFk[2*kb + 4];
      float4 p2 = *(const float4*)&EFk[2*kb + 8];
      float4 p3 = *(const float4*)&EFk[2*kb + 12];
      float wv[8];
      wv[0] = fmaxf(Eu*p0.x, Fu*p0.y); wv[1] = fmaxf(Eu*p0.z, Fu*p0.w);
      wv[2] = fmaxf(Eu*p1.x, Fu*p1.y); wv[3] = fmaxf(Eu*p1.z, Fu*p1.w);
      wv[4] = fmaxf(Eu*p2.x, Fu*p2.y); wv[5] = fmaxf(Eu*p2.z, Fu*p2.w);
      wv[6] = fmaxf(Eu*p3.x, Fu*p3.y); wv[7] = fmaxf(Eu*p3.z, Fu*p3.w);
      u32 bb = ((h ? mhi : mlo) >> (grp*8)) & 0xffu;
      union { u32 uu[4]; short8 v; } pk;
      #pragma unroll
      for (int p = 0; p < 4; ++p) {
        int j = 2*p;
        int slo = ((int)(bb << (31 - j))) >> 31;
        int shi = ((int)(bb << (30 - j))) >> 31;
        u32 msk = __builtin_amdgcn_perm((u32)shi, (u32)slo, 0x05040100u);
        u32 w01 = __builtin_amdgcn_perm(__float_as_uint(wv[j+1]),
                                        __float_as_uint(wv[j]), 0x07060302u);
        pk.uu[p] = w01 & msk;
      }
      af01[h] = pk.v;
    }
    const unsigned short* xb = XT2 + ((size_t)(k0 >> 5))*2048 + l*8;
    #pragma unroll
    for (int q = 0; q < 4; ++q) {
      short8 b0 = *(const short8*)(xb + q*512);
      short8 b1 = *(const short8*)(xb + 2048 + q*512);
      acc[q] = __builtin_amdgcn_mfma_f32_16x16x32_bf16(af01[0], b0, acc[q], 0, 0, 0);
      acc[q] = __builtin_amdgcn_mfma_f32_16x16x32_bf16(af01[1], b1, acc[q], 0, 0, 0);
    }
    accs = __builtin_amdgcn_mfma_f32_16x16x32_bf16(af01[0], bones, accs, 0, 0, 0);
    accs = __builtin_amdgcn_mfma_f32_16x16x32_bf16(af01[1], bones, accs, 0, 0, 0);
  }

  if (row16 == 0) {
    #pragma unroll
    for (int r = 0; r < 4; ++r)
      sumP[(size_t)split*NU + rb*64 + wave*16 + grp*4 + r] = accs[r];
  }
  float* ap = accP + (size_t)split*NU*NF;
  #pragma unroll
  for (int q = 0; q < 4; ++q) {
    #pragma unroll
    for (int r = 0; r < 4; ++r) {
      int uo = rb*64 + wave*16 + grp*4 + r;
      ap[(size_t)uo*NF + q*16 + row16] = acc[q][r];
    }
  }

  // ---- split-K completion: last block for (dir, rb) reduces + finalizes 64 rows ----
  __shared__ int sflag;
  __threadfence();
  __syncthreads();
  if (t == 0) sflag = (atomicAdd(cnt, 1) == SPL - 1);
  __syncthreads();
  if (!sflag) return;
  __threadfence();   // acquire: see other blocks' partials
  #pragma unroll
  for (int q = 0; q < 4; ++q) {
    int item = t + 256*q;            // 64 rows x 16 float4
    int row = item >> 4, f4 = item & 15;
    int uu = rb*64 + row;
    float4 a = make_float4(0.f, 0.f, 0.f, 0.f);
    float den = 0.f;
    #pragma unroll
    for (int s = 0; s < SPL; ++s) {
      float4 p = *(const float4*)&accP[((size_t)s*NU + uu)*NF + f4*4];
      a.x += p.x; a.y += p.y; a.z += p.z; a.w += p.w;
      den += sumP[(size_t)s*NU + uu];
    }
    float4 b4 = *(const float4*)&bias[f4*4];
    float inv = den > 0.f ? 1.f/den : 0.f;
    float4 v;
    v.x = a.x*inv + b4.x; v.y = a.y*inv + b4.y;
    v.z = a.z*inv + b4.z; v.w = a.w*inv + b4.w;
    v.x = v.x > 0.f ? v.x : expm1f(v.x);
    v.y = v.y > 0.f ? v.y : expm1f(v.y);
    v.z = v.z > 0.f ? v.z : expm1f(v.z);
    v.w = v.w > 0.f ? v.w : expm1f(v.w);
    *(float4*)&outB[(size_t)uu*NF + f4*4] = v;
  }
}

__global__ __launch_bounds__(256, 8) void agg_fin(
    const u64* __restrict__ RBt, const u64* __restrict__ CBt,
    const float* __restrict__ EFs, const float* __restrict__ EFt,
    const unsigned short* __restrict__ XT2s, const unsigned short* __restrict__ XT2t,
    float* __restrict__ P0, float* __restrict__ S0,
    float* __restrict__ P1, float* __restrict__ S1,
    int* __restrict__ cnt,
    const float* __restrict__ bias_s, const float* __restrict__ bias_t,
    float* __restrict__ out)
{
  int b = blockIdx.x;
  if (b < 64*SPL0) {
    int rb = b & 63;
    agg_body<0>(rb, b >> 6, RBt, EFt, EFs, XT2s, P0, S0, cnt + rb, bias_s, out);
  } else {
    int b2 = b - 64*SPL0;
    int rb = b2 & 127;
    agg_body<1>(rb, b2 >> 7, CBt, EFs, EFt, XT2t, P1, S1, cnt + 64 + rb, bias_t,
                out + (size_t)N_T*NF);
  }
}

extern "C" void kernel_launch(void* const* d_in, const int* in_sizes, int n_in,
                              void* d_out, int out_size, void* d_ws, size_t ws_size,
                              hipStream_t stream)
{
  const float* hs     = (const float*)d_in[0];
  const float* ht     = (const float*)d_in[1];
  const int*   A      = (const int*)  d_in[2];
  const float* Ws     = (const float*)d_in[3];
  const float* Wt     = (const float*)d_in[4];
  const float* a1     = (const float*)d_in[5];
  const float* bias_s = (const float*)d_in[6];
  const float* bias_t = (const float*)d_in[7];
  float* out = (float*)d_out;

  u64* RBt = (u64*)d_ws;                                     // 4MB
  u64* CBt = RBt + (size_t)(N_S/64)*N_T;                     // 4MB
  unsigned short* XT2s = (unsigned short*)(CBt + (size_t)(N_T/64)*N_S); // 1MB
  unsigned short* XT2t = XT2s + (size_t)NF*N_S;              // 0.5MB
  float* EFs = (float*)(XT2t + (size_t)NF*N_T);              // 2*8192
  float* EFt = EFs + 2*N_S;                                  // 2*4096
  float* P0  = EFt + 2*N_T;                                  // SPL0*4096*64 = 8MB
  float* S0  = P0 + (size_t)SPL0*N_T*NF;                     // SPL0*4096
  float* P1  = S0 + (size_t)SPL0*N_T;                        // SPL1*8192*64 = 8MB
  float* S1  = P1 + (size_t)SPL1*N_S*NF;                     // SPL1*8192
  int*   cnt = (int*)(S1 + (size_t)SPL1*N_S);                // 192 ints

  k1_fused<<<2048 + (N_S + N_T)/4, 256, 0, stream>>>(A, RBt, CBt, hs, ht, Ws, Wt, a1,
                                                     XT2s, XT2t, EFs, EFt, cnt);
  agg_fin<<<64*SPL0 + 128*SPL1, 256, 0, stream>>>(RBt, CBt, EFs, EFt, XT2s, XT2t,
                                                  P0, S0, P1, S1, cnt, bias_s, bias_t, out);
}

// Round 8
// 113.474 us; speedup vs baseline: 2.0564x; 2.0564x over previous
//
#include <hip/hip_runtime.h>
#include <math.h>

#define N_S 8192
#define N_T 4096
#define DIN 128
#define NF  64
#define SPL0 8
#define SPL1 4

typedef __attribute__((ext_vector_type(8))) short short8;
typedef __attribute__((ext_vector_type(4))) float f32x4;
typedef __attribute__((ext_vector_type(4))) int i32x4;
typedef unsigned long long u64;
typedef unsigned int u32;

__device__ __forceinline__ unsigned short f2bf(float x){
  unsigned u = __float_as_uint(x);
  unsigned r = (u + 0x7fffu + ((u >> 16) & 1u)) >> 16;
  return (unsigned short)r;
}

// fragment-major bf16 layout: B-frag for MFMA reads 1KB contiguous per wave
__device__ __forceinline__ size_t xt2_idx(int f, int k){
  return ((size_t)(k >> 5))*2048 + (size_t)((f >> 4)*512 + ((k >> 3) & 3)*128 + (f & 15)*8 + (k & 7));
}

// ---------------- K1: fused {compact A -> bitmasks} + {projections}
// LDS = 6.2KB -> 8 blocks/CU for the A-streaming compact blocks.
__global__ __launch_bounds__(256) void k1_fused(
    const int* __restrict__ A,
    u64* __restrict__ RBt,       // [N_S/64][N_T]  bits of row i over j, chunk-major
    u64* __restrict__ CBt,       // [N_T/64][N_S]  bits of col j over i, chunk-major
    const float* __restrict__ hs, const float* __restrict__ ht,
    const float* __restrict__ Ws, const float* __restrict__ Wt,
    const float* __restrict__ a1,
    unsigned short* __restrict__ XT2s, unsigned short* __restrict__ XT2t,
    float* __restrict__ EFs, float* __restrict__ EFt)
{
  __shared__ __align__(16) float smem[16*64 + 4*DIN];   // 6144 B (compact uses 4160 B)
  int bx = blockIdx.x;
  int t = threadIdx.x;
  if (bx < 2048) {
    // ---- compact 64x256 tile of A ----
    unsigned* T4 = (unsigned*)smem;      // 16*65 words
    int i0 = (bx & 63) * 64;
    int j0 = (bx >> 6) * 256;
    int w = t >> 6, l = t & 63;
    i32x4 v[16];
    #pragma unroll
    for (int it = 0; it < 16; ++it)
      v[it] = __builtin_nontemporal_load(
          (const i32x4*)&A[(size_t)(i0 + w*16 + it)*N_S + j0 + 4*l]);
    #pragma unroll
    for (int rg = 0; rg < 4; ++rg) {
      unsigned p = 0;
      #pragma unroll
      for (int rr = 0; rr < 4; ++rr) {
        i32x4 m = v[rg*4 + rr];
        unsigned nib = (m.x > 0 ? 1u : 0u) | (m.y > 0 ? 2u : 0u)
                     | (m.z > 0 ? 4u : 0u) | (m.w > 0 ? 8u : 0u);
        p |= nib << (8*rr);
      }
      T4[(w*4 + rg)*65 + l] = p;
    }
    __syncthreads();
    {
      int r = t & 63, g = t >> 6;
      u64 bits = 0;
      #pragma unroll
      for (int i = 0; i < 16; ++i) {
        unsigned word = T4[(r >> 2)*65 + g*16 + i];
        unsigned nib = (word >> (8*(r & 3))) & 0xFu;
        bits |= (u64)nib << (4*i);
      }
      RBt[(size_t)((j0 >> 6) + g)*N_T + i0 + r] = bits;
    }
    {
      int c = t;
      u64 bits = 0;
      #pragma unroll
      for (int rg = 0; rg < 16; ++rg) {
        unsigned word = T4[rg*65 + (c >> 2)];
        unsigned x = (word >> (c & 3)) & 0x01010101u;
        unsigned nib = (x * 0x01020408u) >> 24;
        bits |= (u64)(nib & 0xFu) << (4*rg);
      }
      CBt[(size_t)(i0 >> 6)*N_S + j0 + c] = bits;
    }
  } else {
    // ---- proj: 4 rows -> XT2 (fragment-major bf16) + EF tables {exp(p), exp(0.1p)} ----
    // W streamed through LDS in 8 chunks of 16k x 64f (4KB) to keep LDS small.
    int b = bx - 2048;
    float* Wl = smem;                 // 16*64 floats, current chunk
    float* hrow = smem + 16*64;       // 4*128 floats
    bool is_s = b < (N_S/4);
    const float* h; const float* W; const float* av;
    unsigned short* XT; float* EFd; int r0;
    if (is_s) { r0 = b*4;           h = hs; W = Ws; av = a1 + 64; XT = XT2s; EFd = EFs; }
    else      { r0 = (b - N_S/4)*4; h = ht; W = Wt; av = a1;      XT = XT2t; EFd = EFt; }
    for (int i = t; i < 4*DIN; i += 256) hrow[i] = h[(size_t)r0*DIN + i];
    int f = t & 63, sr = t >> 6;
    float acc = 0.f;
    #pragma unroll
    for (int c = 0; c < 8; ++c) {
      __syncthreads();               // previous chunk fully consumed
      #pragma unroll
      for (int i = t; i < 16*64; i += 256) Wl[i] = W[(c*16 + (i >> 6))*NF + (i & 63)];
      __syncthreads();
      #pragma unroll
      for (int kk = 0; kk < 16; ++kk) acc += hrow[sr*DIN + c*16 + kk] * Wl[kk*64 + f];
    }
    int r = r0 + sr;
    XT[xt2_idx(f, r)] = f2bf(acc);
    float p = acc * av[f];
    #pragma unroll
    for (int o = 32; o > 0; o >>= 1) p += __shfl_xor(p, o, 64);
    if (f == 0) { EFd[2*r] = __expf(p); EFd[2*r + 1] = __expf(0.1f*p); }
  }
}

// ---------------- K2: fused both-direction masked aggregation via MFMA bf16.
// w(u,k) = bit(u,k) * max(Eu*Ek, Fu*Fk)  (= exp(lrelu(bu+vk)); exp monotone, no shift needed)
// Denominators via ones-B MFMA. No atomics, no fences: partials per k-split block.
template<int DIR>
__device__ __forceinline__ void agg_body(
    int rb, int split,
    const u64* __restrict__ MBt,
    const float* __restrict__ EFu, const float* __restrict__ EFk,
    const unsigned short* __restrict__ XT2,
    float* __restrict__ accP,   // [SPL][NU][NF]
    float* __restrict__ sumP)   // [SPL][NU]
{
  constexpr int NK = (DIR == 0) ? N_S : N_T;
  constexpr int NU = (DIR == 0) ? N_T : N_S;
  constexpr int SPL = (DIR == 0) ? SPL0 : SPL1;
  constexpr int KCH = NK / SPL;
  int t = threadIdx.x;
  int wave = t >> 6, l = t & 63;
  int row16 = l & 15, grp = l >> 4;
  int u = rb*64 + wave*16 + row16;
  float2 ef = *(const float2*)&EFu[2*u];
  float Eu = ef.x, Fu = ef.y;
  f32x4 acc[4];
  #pragma unroll
  for (int q = 0; q < 4; ++q) { acc[q][0]=0.f; acc[q][1]=0.f; acc[q][2]=0.f; acc[q][3]=0.f; }
  f32x4 accs; accs[0]=0.f; accs[1]=0.f; accs[2]=0.f; accs[3]=0.f;
  short8 bones;
  #pragma unroll
  for (int j = 0; j < 8; ++j) bones[j] = (short)0x3F80;   // bf16(1.0)
  int kc0 = split * KCH;

  #pragma unroll 2
  for (int k0 = kc0; k0 < kc0 + KCH; k0 += 64) {
    u64 mb = MBt[(size_t)(k0 >> 6)*NU + u];
    u32 mlo = (u32)mb, mhi = (u32)(mb >> 32);
    short8 af01[2];
    #pragma unroll
    for (int h = 0; h < 2; ++h) {
      int kb = k0 + 32*h + grp*8;
      float4 p0 = *(const float4*)&EFk[2*kb];
      float4 p1 = *(const float4*)&EFk[2*kb + 4];
      float4 p2 = *(const float4*)&EFk[2*kb + 8];
      float4 p3 = *(const float4*)&EFk[2*kb + 12];
      float wv[8];
      wv[0] = fmaxf(Eu*p0.x, Fu*p0.y); wv[1] = fmaxf(Eu*p0.z, Fu*p0.w);
      wv[2] = fmaxf(Eu*p1.x, Fu*p1.y); wv[3] = fmaxf(Eu*p1.z, Fu*p1.w);
      wv[4] = fmaxf(Eu*p2.x, Fu*p2.y); wv[5] = fmaxf(Eu*p2.z, Fu*p2.w);
      wv[6] = fmaxf(Eu*p3.x, Fu*p3.y); wv[7] = fmaxf(Eu*p3.z, Fu*p3.w);
      u32 bb = ((h ? mhi : mlo) >> (grp*8)) & 0xffu;
      union { u32 uu[4]; short8 v; } pk;
      #pragma unroll
      for (int p = 0; p < 4; ++p) {
        int j = 2*p;
        int slo = ((int)(bb << (31 - j))) >> 31;
        int shi = ((int)(bb << (30 - j))) >> 31;
        u32 msk = __builtin_amdgcn_perm((u32)shi, (u32)slo, 0x05040100u);
        u32 w01 = __builtin_amdgcn_perm(__float_as_uint(wv[j+1]),
                                        __float_as_uint(wv[j]), 0x07060302u);
        pk.uu[p] = w01 & msk;
      }
      af01[h] = pk.v;
    }
    const unsigned short* xb = XT2 + ((size_t)(k0 >> 5))*2048 + l*8;
    #pragma unroll
    for (int q = 0; q < 4; ++q) {
      short8 b0 = *(const short8*)(xb + q*512);
      short8 b1 = *(const short8*)(xb + 2048 + q*512);
      acc[q] = __builtin_amdgcn_mfma_f32_16x16x32_bf16(af01[0], b0, acc[q], 0, 0, 0);
      acc[q] = __builtin_amdgcn_mfma_f32_16x16x32_bf16(af01[1], b1, acc[q], 0, 0, 0);
    }
    accs = __builtin_amdgcn_mfma_f32_16x16x32_bf16(af01[0], bones, accs, 0, 0, 0);
    accs = __builtin_amdgcn_mfma_f32_16x16x32_bf16(af01[1], bones, accs, 0, 0, 0);
  }

  if (row16 == 0) {
    #pragma unroll
    for (int r = 0; r < 4; ++r)
      sumP[(size_t)split*NU + rb*64 + wave*16 + grp*4 + r] = accs[r];
  }
  float* ap = accP + (size_t)split*NU*NF;
  #pragma unroll
  for (int q = 0; q < 4; ++q) {
    #pragma unroll
    for (int r = 0; r < 4; ++r) {
      int uo = rb*64 + wave*16 + grp*4 + r;
      ap[(size_t)uo*NF + q*16 + row16] = acc[q][r];
    }
  }
}

__global__ __launch_bounds__(256, 8) void agg_fused(
    const u64* __restrict__ RBt, const u64* __restrict__ CBt,
    const float* __restrict__ EFs, const float* __restrict__ EFt,
    const unsigned short* __restrict__ XT2s, const unsigned short* __restrict__ XT2t,
    float* __restrict__ P0, float* __restrict__ S0,
    float* __restrict__ P1, float* __restrict__ S1)
{
  int b = blockIdx.x;
  if (b < 64*SPL0) {
    agg_body<0>(b & 63, b >> 6, RBt, EFt, EFs, XT2s, P0, S0);
  } else {
    int b2 = b - 64*SPL0;
    agg_body<1>(b2 & 127, b2 >> 7, CBt, EFs, EFt, XT2t, P1, S1);
  }
}

// ---------------- K3: reduce partials + normalize + bias + elu, float4-vectorized
__global__ __launch_bounds__(256) void finalize_kernel(
    const float* __restrict__ P0, const float* __restrict__ S0,
    const float* __restrict__ P1, const float* __restrict__ S1,
    const float* __restrict__ bias_s, const float* __restrict__ bias_t,
    float* __restrict__ out)
{
  int tid = blockIdx.x*256 + threadIdx.x;   // one float4 per thread
  const int n0 = N_T*NF/4;
  float4 a = make_float4(0.f, 0.f, 0.f, 0.f);
  float den = 0.f;
  float4 bias;
  if (tid < n0) {
    int u = tid >> 4, fq = (tid & 15)*4;
    #pragma unroll
    for (int s = 0; s < SPL0; ++s) {
      float4 p = *(const float4*)&P0[((size_t)s*N_T + u)*NF + fq];
      a.x += p.x; a.y += p.y; a.z += p.z; a.w += p.w;
      den += S0[(size_t)s*N_T + u];
    }
    bias = *(const float4*)&bias_s[fq];
  } else {
    int i2 = tid - n0;
    int u = i2 >> 4, fq = (i2 & 15)*4;
    #pragma unroll
    for (int s = 0; s < SPL1; ++s) {
      float4 p = *(const float4*)&P1[((size_t)s*N_S + u)*NF + fq];
      a.x += p.x; a.y += p.y; a.z += p.z; a.w += p.w;
      den += S1[(size_t)s*N_S + u];
    }
    bias = *(const float4*)&bias_t[fq];
  }
  float inv = den > 0.f ? 1.f/den : 0.f;
  float4 v;
  v.x = a.x*inv + bias.x; v.y = a.y*inv + bias.y;
  v.z = a.z*inv + bias.z; v.w = a.w*inv + bias.w;
  v.x = v.x > 0.f ? v.x : expm1f(v.x);
  v.y = v.y > 0.f ? v.y : expm1f(v.y);
  v.z = v.z > 0.f ? v.z : expm1f(v.z);
  v.w = v.w > 0.f ? v.w : expm1f(v.w);
  *(float4*)&out[tid*4] = v;
}

extern "C" void kernel_launch(void* const* d_in, const int* in_sizes, int n_in,
                              void* d_out, int out_size, void* d_ws, size_t ws_size,
                              hipStream_t stream)
{
  const float* hs     = (const float*)d_in[0];
  const float* ht     = (const float*)d_in[1];
  const int*   A      = (const int*)  d_in[2];
  const float* Ws     = (const float*)d_in[3];
  const float* Wt     = (const float*)d_in[4];
  const float* a1     = (const float*)d_in[5];
  const float* bias_s = (const float*)d_in[6];
  const float* bias_t = (const float*)d_in[7];
  float* out = (float*)d_out;

  u64* RBt = (u64*)d_ws;                                     // 4MB
  u64* CBt = RBt + (size_t)(N_S/64)*N_T;                     // 4MB
  unsigned short* XT2s = (unsigned short*)(CBt + (size_t)(N_T/64)*N_S); // 1MB
  unsigned short* XT2t = XT2s + (size_t)NF*N_S;              // 0.5MB
  float* EFs = (float*)(XT2t + (size_t)NF*N_T);              // 2*8192
  float* EFt = EFs + 2*N_S;                                  // 2*4096
  float* P0  = EFt + 2*N_T;                                  // SPL0*4096*64 = 8MB
  float* S0  = P0 + (size_t)SPL0*N_T*NF;                     // SPL0*4096
  float* P1  = S0 + (size_t)SPL0*N_T;                        // SPL1*8192*64 = 8MB
  float* S1  = P1 + (size_t)SPL1*N_S*NF;                     // SPL1*8192

  k1_fused<<<2048 + (N_S + N_T)/4, 256, 0, stream>>>(A, RBt, CBt, hs, ht, Ws, Wt, a1,
                                                     XT2s, XT2t, EFs, EFt);
  agg_fused<<<64*SPL0 + 128*SPL1, 256, 0, stream>>>(RBt, CBt, EFs, EFt, XT2s, XT2t,
                                                    P0, S0, P1, S1);
  finalize_kernel<<<(N_T*NF + N_S*NF)/1024, 256, 0, stream>>>(P0, S0, P1, S1,
                                                              bias_s, bias_t, out);
}

// Round 9
// 89.109 us; speedup vs baseline: 2.6187x; 1.2734x over previous
//
#include <hip/hip_runtime.h>
#include <math.h>

#define N_S 8192
#define N_T 4096
#define DIN 128
#define NF  64
#define SPL0 8
#define SPL1 4

typedef __attribute__((ext_vector_type(8))) short short8;
typedef __attribute__((ext_vector_type(4))) float f32x4;
typedef __attribute__((ext_vector_type(4))) int i32x4;
typedef unsigned long long u64;
typedef unsigned int u32;

__device__ __forceinline__ unsigned short f2bf(float x){
  unsigned u = __float_as_uint(x);
  unsigned r = (u + 0x7fffu + ((u >> 16) & 1u)) >> 16;
  return (unsigned short)r;
}

// fragment-major bf16 layout: B-frag for MFMA reads 1KB contiguous per wave
__device__ __forceinline__ size_t xt2_idx(int f, int k){
  return ((size_t)(k >> 5))*2048 + (size_t)((f >> 4)*512 + ((k >> 3) & 3)*128 + (f & 15)*8 + (k & 7));
}

// ---------------- K1: fused {stream-compact A -> row bitmask RBt} + {projections}
// Compact blocks read A PERFECTLY SEQUENTIALLY: block b owns rows {2b,2b+1} (64KB
// contiguous); each wave streams 16KB of coalesced int4. Bits packed via shfl tree.
__global__ __launch_bounds__(256) void k1_fused(
    const int* __restrict__ A,
    u64* __restrict__ RBt,       // [N_S/64][N_T]  bits of row i over j, chunk-major
    const float* __restrict__ hs, const float* __restrict__ ht,
    const float* __restrict__ Ws, const float* __restrict__ Wt,
    const float* __restrict__ a1,
    unsigned short* __restrict__ XT2s, unsigned short* __restrict__ XT2t,
    float* __restrict__ EFs, float* __restrict__ EFt)
{
  __shared__ __align__(16) float smem[DIN*NF + 4*DIN];   // 34816 B; compact uses 2KB alias
  int bx = blockIdx.x;
  int t = threadIdx.x;
  if (bx < 2048) {
    // ---- stream-compact rows 2bx, 2bx+1 ----
    u64* rbS = (u64*)smem;               // [2][128]
    int w = t >> 6, l = t & 63;
    int i = 2*bx + (w >> 1);
    int h = w & 1;
    const int* base = A + (size_t)i*N_S + h*4096;
    #pragma unroll
    for (int it = 0; it < 16; ++it) {
      i32x4 v = *(const i32x4*)(base + it*256 + 4*l);
      u32 nib = (v.x > 0 ? 1u : 0u) | (v.y > 0 ? 2u : 0u)
              | (v.z > 0 ? 4u : 0u) | (v.w > 0 ? 8u : 0u);
      u32 b8  = nib | (((u32)__shfl_xor((int)nib, 1, 64)) << 4);
      u32 b16 = b8  | (((u32)__shfl_xor((int)b8,  2, 64)) << 8);
      u32 b32 = b16 | (((u32)__shfl_xor((int)b16, 4, 64)) << 16);
      u32 hi  = (u32)__shfl_xor((int)b32, 8, 64);
      if ((l & 15) == 0)
        rbS[(size_t)(w>>1)*128 + h*64 + it*4 + (l>>4)] = (u64)b32 | ((u64)hi << 32);
    }
    __syncthreads();
    int wi = t >> 1, ri = t & 1;
    RBt[(size_t)wi*N_T + 2*bx + ri] = rbS[(size_t)ri*128 + wi];
  } else {
    // ---- proj: 4 rows -> XT2 (fragment-major bf16) + EF tables {exp(p), exp(0.1p)} ----
    int b = bx - 2048;
    float* Wl = smem;
    float* hrow = smem + DIN*NF;
    bool is_s = b < (N_S/4);
    const float* h; const float* W; const float* av;
    unsigned short* XT; float* EFd; int r0;
    if (is_s) { r0 = b*4;           h = hs; W = Ws; av = a1 + 64; XT = XT2s; EFd = EFs; }
    else      { r0 = (b - N_S/4)*4; h = ht; W = Wt; av = a1;      XT = XT2t; EFd = EFt; }
    for (int i = t; i < DIN*NF; i += 256) Wl[i] = W[i];
    for (int i = t; i < 4*DIN;  i += 256) hrow[i] = h[(size_t)r0*DIN + i];
    __syncthreads();
    int f = t & 63, sr = t >> 6;
    float acc = 0.f;
    #pragma unroll 8
    for (int k = 0; k < DIN; ++k) acc += hrow[sr*DIN + k] * Wl[k*NF + f];
    int r = r0 + sr;
    XT[xt2_idx(f, r)] = f2bf(acc);
    float p = acc * av[f];
    #pragma unroll
    for (int o = 32; o > 0; o >>= 1) p += __shfl_xor(p, o, 64);
    if (f == 0) { EFd[2*r] = __expf(p); EFd[2*r + 1] = __expf(0.1f*p); }
  }
}

// ---------------- K1b: 64x64 bit-matrix transpose RBt -> CBt (8MB, L2/L3-resident)
// Lane l holds row (i = ic*64+l) bits over j; butterfly produces column words.
__global__ __launch_bounds__(256) void btr_kernel(
    const u64* __restrict__ RBt,
    u64* __restrict__ CBt)       // [N_T/64][N_S]  bits of col j over i, chunk-major
{
  int id = blockIdx.x*4 + (threadIdx.x >> 6);
  int l = threadIdx.x & 63;
  int jc = id >> 6, ic = id & 63;
  u64 x = RBt[(size_t)jc*N_T + ic*64 + l];
  const u64 MM[6] = {0x00000000FFFFFFFFull, 0x0000FFFF0000FFFFull, 0x00FF00FF00FF00FFull,
                     0x0F0F0F0F0F0F0F0Full, 0x3333333333333333ull, 0x5555555555555555ull};
  const int DD[6] = {32, 16, 8, 4, 2, 1};
  #pragma unroll
  for (int s = 0; s < 6; ++s) {
    int d = DD[s]; u64 M = MM[s];
    u32 ylo = (u32)__shfl_xor((int)(u32)x, d, 64);
    u32 yhi = (u32)__shfl_xor((int)(u32)(x >> 32), d, 64);
    u64 y = (u64)ylo | ((u64)yhi << 32);
    x = ((l & d) == 0) ? ((x & M) | ((y & M) << d))
                       : ((x & ~M) | ((y & ~M) >> d));
  }
  CBt[(size_t)ic*N_S + jc*64 + l] = x;
}

// ---------------- K2: fused both-direction masked aggregation via MFMA bf16.
// w(u,k) = bit(u,k) * max(Eu*Ek, Fu*Fk)  (= exp(lrelu(bu+vk)); exp monotone, no shift needed)
template<int DIR>
__device__ __forceinline__ void agg_body(
    int rb, int split,
    const u64* __restrict__ MBt,
    const float* __restrict__ EFu, const float* __restrict__ EFk,
    const unsigned short* __restrict__ XT2,
    float* __restrict__ accP,   // [SPL][NU][NF]
    float* __restrict__ sumP)   // [SPL][NU]
{
  constexpr int NK = (DIR == 0) ? N_S : N_T;
  constexpr int NU = (DIR == 0) ? N_T : N_S;
  constexpr int SPL = (DIR == 0) ? SPL0 : SPL1;
  constexpr int KCH = NK / SPL;
  int t = threadIdx.x;
  int wave = t >> 6, l = t & 63;
  int row16 = l & 15, grp = l >> 4;
  int u = rb*64 + wave*16 + row16;
  float2 ef = *(const float2*)&EFu[2*u];
  float Eu = ef.x, Fu = ef.y;
  f32x4 acc[4];
  #pragma unroll
  for (int q = 0; q < 4; ++q) { acc[q][0]=0.f; acc[q][1]=0.f; acc[q][2]=0.f; acc[q][3]=0.f; }
  f32x4 accs; accs[0]=0.f; accs[1]=0.f; accs[2]=0.f; accs[3]=0.f;
  short8 bones;
  #pragma unroll
  for (int j = 0; j < 8; ++j) bones[j] = (short)0x3F80;   // bf16(1.0)
  int kc0 = split * KCH;

  #pragma unroll 2
  for (int k0 = kc0; k0 < kc0 + KCH; k0 += 64) {
    u64 mb = MBt[(size_t)(k0 >> 6)*NU + u];
    u32 mlo = (u32)mb, mhi = (u32)(mb >> 32);
    short8 af01[2];
    #pragma unroll
    for (int h = 0; h < 2; ++h) {
      int kb = k0 + 32*h + grp*8;
      float4 p0 = *(const float4*)&EFk[2*kb];
      float4 p1 = *(const float4*)&EFk[2*kb + 4];
      float4 p2 = *(const float4*)&EFk[2*kb + 8];
      float4 p3 = *(const float4*)&EFk[2*kb + 12];
      float wv[8];
      wv[0] = fmaxf(Eu*p0.x, Fu*p0.y); wv[1] = fmaxf(Eu*p0.z, Fu*p0.w);
      wv[2] = fmaxf(Eu*p1.x, Fu*p1.y); wv[3] = fmaxf(Eu*p1.z, Fu*p1.w);
      wv[4] = fmaxf(Eu*p2.x, Fu*p2.y); wv[5] = fmaxf(Eu*p2.z, Fu*p2.w);
      wv[6] = fmaxf(Eu*p3.x, Fu*p3.y); wv[7] = fmaxf(Eu*p3.z, Fu*p3.w);
      u32 bb = ((h ? mhi : mlo) >> (grp*8)) & 0xffu;
      union { u32 uu[4]; short8 v; } pk;
      #pragma unroll
      for (int p = 0; p < 4; ++p) {
        int j = 2*p;
        int slo = ((int)(bb << (31 - j))) >> 31;
        int shi = ((int)(bb << (30 - j))) >> 31;
        u32 msk = __builtin_amdgcn_perm((u32)shi, (u32)slo, 0x05040100u);
        u32 w01 = __builtin_amdgcn_perm(__float_as_uint(wv[j+1]),
                                        __float_as_uint(wv[j]), 0x07060302u);
        pk.uu[p] = w01 & msk;
      }
      af01[h] = pk.v;
    }
    const unsigned short* xb = XT2 + ((size_t)(k0 >> 5))*2048 + l*8;
    #pragma unroll
    for (int q = 0; q < 4; ++q) {
      short8 b0 = *(const short8*)(xb + q*512);
      short8 b1 = *(const short8*)(xb + 2048 + q*512);
      acc[q] = __builtin_amdgcn_mfma_f32_16x16x32_bf16(af01[0], b0, acc[q], 0, 0, 0);
      acc[q] = __builtin_amdgcn_mfma_f32_16x16x32_bf16(af01[1], b1, acc[q], 0, 0, 0);
    }
    accs = __builtin_amdgcn_mfma_f32_16x16x32_bf16(af01[0], bones, accs, 0, 0, 0);
    accs = __builtin_amdgcn_mfma_f32_16x16x32_bf16(af01[1], bones, accs, 0, 0, 0);
  }

  if (row16 == 0) {
    #pragma unroll
    for (int r = 0; r < 4; ++r)
      sumP[(size_t)split*NU + rb*64 + wave*16 + grp*4 + r] = accs[r];
  }
  float* ap = accP + (size_t)split*NU*NF;
  #pragma unroll
  for (int q = 0; q < 4; ++q) {
    #pragma unroll
    for (int r = 0; r < 4; ++r) {
      int uo = rb*64 + wave*16 + grp*4 + r;
      ap[(size_t)uo*NF + q*16 + row16] = acc[q][r];
    }
  }
}

__global__ __launch_bounds__(256, 8) void agg_fused(
    const u64* __restrict__ RBt, const u64* __restrict__ CBt,
    const float* __restrict__ EFs, const float* __restrict__ EFt,
    const unsigned short* __restrict__ XT2s, const unsigned short* __restrict__ XT2t,
    float* __restrict__ P0, float* __restrict__ S0,
    float* __restrict__ P1, float* __restrict__ S1)
{
  int b = blockIdx.x;
  if (b < 64*SPL0) {
    agg_body<0>(b & 63, b >> 6, RBt, EFt, EFs, XT2s, P0, S0);
  } else {
    int b2 = b - 64*SPL0;
    agg_body<1>(b2 & 127, b2 >> 7, CBt, EFs, EFt, XT2t, P1, S1);
  }
}

// ---------------- K3: reduce partials + normalize + bias + elu, float4-vectorized
__global__ __launch_bounds__(256) void finalize_kernel(
    const float* __restrict__ P0, const float* __restrict__ S0,
    const float* __restrict__ P1, const float* __restrict__ S1,
    const float* __restrict__ bias_s, const float* __restrict__ bias_t,
    float* __restrict__ out)
{
  int tid = blockIdx.x*256 + threadIdx.x;   // one float4 per thread
  const int n0 = N_T*NF/4;
  float4 a = make_float4(0.f, 0.f, 0.f, 0.f);
  float den = 0.f;
  float4 bias;
  if (tid < n0) {
    int u = tid >> 4, fq = (tid & 15)*4;
    #pragma unroll
    for (int s = 0; s < SPL0; ++s) {
      float4 p = *(const float4*)&P0[((size_t)s*N_T + u)*NF + fq];
      a.x += p.x; a.y += p.y; a.z += p.z; a.w += p.w;
      den += S0[(size_t)s*N_T + u];
    }
    bias = *(const float4*)&bias_s[fq];
  } else {
    int i2 = tid - n0;
    int u = i2 >> 4, fq = (i2 & 15)*4;
    #pragma unroll
    for (int s = 0; s < SPL1; ++s) {
      float4 p = *(const float4*)&P1[((size_t)s*N_S + u)*NF + fq];
      a.x += p.x; a.y += p.y; a.z += p.z; a.w += p.w;
      den += S1[(size_t)s*N_S + u];
    }
    bias = *(const float4*)&bias_t[fq];
  }
  float inv = den > 0.f ? 1.f/den : 0.f;
  float4 v;
  v.x = a.x*inv + bias.x; v.y = a.y*inv + bias.y;
  v.z = a.z*inv + bias.z; v.w = a.w*inv + bias.w;
  v.x = v.x > 0.f ? v.x : expm1f(v.x);
  v.y = v.y > 0.f ? v.y : expm1f(v.y);
  v.z = v.z > 0.f ? v.z : expm1f(v.z);
  v.w = v.w > 0.f ? v.w : expm1f(v.w);
  *(float4*)&out[tid*4] = v;
}

extern "C" void kernel_launch(void* const* d_in, const int* in_sizes, int n_in,
                              void* d_out, int out_size, void* d_ws, size_t ws_size,
                              hipStream_t stream)
{
  const float* hs     = (const float*)d_in[0];
  const float* ht     = (const float*)d_in[1];
  const int*   A      = (const int*)  d_in[2];
  const float* Ws     = (const float*)d_in[3];
  const float* Wt     = (const float*)d_in[4];
  const float* a1     = (const float*)d_in[5];
  const float* bias_s = (const float*)d_in[6];
  const float* bias_t = (const float*)d_in[7];
  float* out = (float*)d_out;

  u64* RBt = (u64*)d_ws;                                     // 4MB
  u64* CBt = RBt + (size_t)(N_S/64)*N_T;                     // 4MB
  unsigned short* XT2s = (unsigned short*)(CBt + (size_t)(N_T/64)*N_S); // 1MB
  unsigned short* XT2t = XT2s + (size_t)NF*N_S;              // 0.5MB
  float* EFs = (float*)(XT2t + (size_t)NF*N_T);              // 2*8192
  float* EFt = EFs + 2*N_S;                                  // 2*4096
  float* P0  = EFt + 2*N_T;                                  // SPL0*4096*64 = 8MB
  float* S0  = P0 + (size_t)SPL0*N_T*NF;                     // SPL0*4096
  float* P1  = S0 + (size_t)SPL0*N_T;                        // SPL1*8192*64 = 8MB
  float* S1  = P1 + (size_t)SPL1*N_S*NF;                     // SPL1*8192

  k1_fused<<<2048 + (N_S + N_T)/4, 256, 0, stream>>>(A, RBt, hs, ht, Ws, Wt, a1,
                                                     XT2s, XT2t, EFs, EFt);
  btr_kernel<<<(N_S/64)*(N_T/64)/4, 256, 0, stream>>>(RBt, CBt);
  agg_fused<<<64*SPL0 + 128*SPL1, 256, 0, stream>>>(RBt, CBt, EFs, EFt, XT2s, XT2t,
                                                    P0, S0, P1, S1);
  finalize_kernel<<<(N_T*NF + N_S*NF)/1024, 256, 0, stream>>>(P0, S0, P1, S1,
                                                              bias_s, bias_t, out);
}

// Round 10
// 84.356 us; speedup vs baseline: 2.7663x; 1.0563x over previous
//
#include <hip/hip_runtime.h>
#include <math.h>

#define N_S 8192
#define N_T 4096
#define DIN 128
#define NF  64
#define SPL0 8
#define SPL1 4

typedef __attribute__((ext_vector_type(8))) short short8;
typedef __attribute__((ext_vector_type(4))) float f32x4;
typedef __attribute__((ext_vector_type(4))) int i32x4;
typedef unsigned long long u64;
typedef unsigned int u32;

__device__ __forceinline__ unsigned short f2bf(float x){
  unsigned u = __float_as_uint(x);
  unsigned r = (u + 0x7fffu + ((u >> 16) & 1u)) >> 16;
  return (unsigned short)r;
}

// fragment-major bf16 layout: B-frag for MFMA reads 1KB contiguous per wave
__device__ __forceinline__ size_t xt2_idx(int f, int k){
  return ((size_t)(k >> 5))*2048 + (size_t)((f >> 4)*512 + ((k >> 3) & 3)*128 + (f & 15)*8 + (k & 7));
}

// ---------------- K1: fused {stream-compact A -> row bitmask RBt} + {projections}
// Compact blocks read A PERFECTLY SEQUENTIALLY: block b owns rows {2b,2b+1} (64KB
// contiguous); each wave streams 16KB of coalesced int4. Bits packed via shfl tree.
// NOTE: no nontemporal on A — it is L3-resident across replays (R8 lesson).
__global__ __launch_bounds__(256) void k1_fused(
    const int* __restrict__ A,
    u64* __restrict__ RBt,       // [N_S/64][N_T]  bits of row i over j, chunk-major
    const float* __restrict__ hs, const float* __restrict__ ht,
    const float* __restrict__ Ws, const float* __restrict__ Wt,
    const float* __restrict__ a1,
    unsigned short* __restrict__ XT2s, unsigned short* __restrict__ XT2t,
    float* __restrict__ EFs, float* __restrict__ EFt)
{
  __shared__ __align__(16) float smem[DIN*NF + 4*DIN];   // 34816 B; compact uses 2KB alias
  int bx = blockIdx.x;
  int t = threadIdx.x;
  if (bx < 2048) {
    // ---- stream-compact rows 2bx, 2bx+1 ----
    u64* rbS = (u64*)smem;               // [2][128]
    int w = t >> 6, l = t & 63;
    int i = 2*bx + (w >> 1);
    int h = w & 1;
    const int* base = A + (size_t)i*N_S + h*4096;
    #pragma unroll
    for (int it = 0; it < 16; ++it) {
      i32x4 v = *(const i32x4*)(base + it*256 + 4*l);
      u32 nib = (v.x > 0 ? 1u : 0u) | (v.y > 0 ? 2u : 0u)
              | (v.z > 0 ? 4u : 0u) | (v.w > 0 ? 8u : 0u);
      u32 b8  = nib | (((u32)__shfl_xor((int)nib, 1, 64)) << 4);
      u32 b16 = b8  | (((u32)__shfl_xor((int)b8,  2, 64)) << 8);
      u32 b32 = b16 | (((u32)__shfl_xor((int)b16, 4, 64)) << 16);
      u32 hi  = (u32)__shfl_xor((int)b32, 8, 64);
      if ((l & 15) == 0)
        rbS[(size_t)(w>>1)*128 + h*64 + it*4 + (l>>4)] = (u64)b32 | ((u64)hi << 32);
    }
    __syncthreads();
    int wi = t >> 1, ri = t & 1;
    RBt[(size_t)wi*N_T + 2*bx + ri] = rbS[(size_t)ri*128 + wi];
  } else {
    // ---- proj: 4 rows -> XT2 (fragment-major bf16) + EF tables {exp(p), exp(0.1p)} ----
    int b = bx - 2048;
    float* Wl = smem;
    float* hrow = smem + DIN*NF;
    bool is_s = b < (N_S/4);
    const float* h; const float* W; const float* av;
    unsigned short* XT; float* EFd; int r0;
    if (is_s) { r0 = b*4;           h = hs; W = Ws; av = a1 + 64; XT = XT2s; EFd = EFs; }
    else      { r0 = (b - N_S/4)*4; h = ht; W = Wt; av = a1;      XT = XT2t; EFd = EFt; }
    for (int i = t; i < DIN*NF; i += 256) Wl[i] = W[i];
    for (int i = t; i < 4*DIN;  i += 256) hrow[i] = h[(size_t)r0*DIN + i];
    __syncthreads();
    int f = t & 63, sr = t >> 6;
    float acc = 0.f;
    #pragma unroll 8
    for (int k = 0; k < DIN; ++k) acc += hrow[sr*DIN + k] * Wl[k*NF + f];
    int r = r0 + sr;
    XT[xt2_idx(f, r)] = f2bf(acc);
    float p = acc * av[f];
    #pragma unroll
    for (int o = 32; o > 0; o >>= 1) p += __shfl_xor(p, o, 64);
    if (f == 0) { EFd[2*r] = __expf(p); EFd[2*r + 1] = __expf(0.1f*p); }
  }
}

// ---------------- K2: fused both-direction masked aggregation via MFMA bf16.
// Both directions feed off RBt[jw][i] (bits of row i over j-chunk jw):
//   DIR0 (out rows u=i, k=j): mask word = RBt[k0>>6][u]  (direct)
//   DIR1 (out rows u=j, k=i): block prologue transposes its 16 needed 64x64
//        bit-tiles of RBt into LDS via the butterfly; main loop reads LDS.
// w(u,k) = bit(u,k) * max(Eu*Ek, Fu*Fk)  (= exp(lrelu(bu+vk)); exp monotone, no shift needed)
template<int DIR>
__device__ __forceinline__ void agg_body(
    int rb, int split,
    const u64* __restrict__ RBt,
    const float* __restrict__ EFu, const float* __restrict__ EFk,
    const unsigned short* __restrict__ XT2,
    float* __restrict__ accP,   // [SPL][NU][NF]
    float* __restrict__ sumP,   // [SPL][NU]
    u64* cbS)                   // LDS [16][64], DIR1 only
{
  constexpr int NK = (DIR == 0) ? N_S : N_T;
  constexpr int NU = (DIR == 0) ? N_T : N_S;
  constexpr int SPL = (DIR == 0) ? SPL0 : SPL1;
  constexpr int KCH = NK / SPL;
  int t = threadIdx.x;
  int wave = t >> 6, l = t & 63;
  int row16 = l & 15, grp = l >> 4;
  int u = rb*64 + wave*16 + row16;
  int kc0 = split * KCH;

  if (DIR == 1) {
    // prologue: butterfly-transpose 16 tiles RBt[rb][kc0 + c*64 + l] -> cbS[c][l]
    const u64 MM[6] = {0x00000000FFFFFFFFull, 0x0000FFFF0000FFFFull, 0x00FF00FF00FF00FFull,
                       0x0F0F0F0F0F0F0F0Full, 0x3333333333333333ull, 0x5555555555555555ull};
    const int DD[6] = {32, 16, 8, 4, 2, 1};
    #pragma unroll
    for (int cc = 0; cc < 4; ++cc) {
      int c = wave*4 + cc;
      u64 x = RBt[(size_t)rb*N_T + kc0 + c*64 + l];
      #pragma unroll
      for (int s = 0; s < 6; ++s) {
        int d = DD[s]; u64 M = MM[s];
        u32 ylo = (u32)__shfl_xor((int)(u32)x, d, 64);
        u32 yhi = (u32)__shfl_xor((int)(u32)(x >> 32), d, 64);
        u64 y = (u64)ylo | ((u64)yhi << 32);
        x = ((l & d) == 0) ? ((x & M) | ((y & M) << d))
                           : ((x & ~M) | ((y & ~M) >> d));
      }
      cbS[c*64 + l] = x;        // bits over i in chunk (kc0/64 + c) for col u=rb*64+l
    }
    __syncthreads();
  }

  float2 ef = *(const float2*)&EFu[2*u];
  float Eu = ef.x, Fu = ef.y;
  f32x4 acc[4];
  #pragma unroll
  for (int q = 0; q < 4; ++q) { acc[q][0]=0.f; acc[q][1]=0.f; acc[q][2]=0.f; acc[q][3]=0.f; }
  f32x4 accs; accs[0]=0.f; accs[1]=0.f; accs[2]=0.f; accs[3]=0.f;
  short8 bones;
  #pragma unroll
  for (int j = 0; j < 8; ++j) bones[j] = (short)0x3F80;   // bf16(1.0)

  #pragma unroll 2
  for (int k0 = kc0; k0 < kc0 + KCH; k0 += 64) {
    u64 mb = (DIR == 0) ? RBt[(size_t)(k0 >> 6)*NU + u]
                        : cbS[((k0 - kc0) >> 6)*64 + wave*16 + row16];
    u32 mlo = (u32)mb, mhi = (u32)(mb >> 32);
    short8 af01[2];
    #pragma unroll
    for (int h = 0; h < 2; ++h) {
      int kb = k0 + 32*h + grp*8;
      float4 p0 = *(const float4*)&EFk[2*kb];
      float4 p1 = *(const float4*)&EFk[2*kb + 4];
      float4 p2 = *(const float4*)&EFk[2*kb + 8];
      float4 p3 = *(const float4*)&EFk[2*kb + 12];
      float wv[8];
      wv[0] = fmaxf(Eu*p0.x, Fu*p0.y); wv[1] = fmaxf(Eu*p0.z, Fu*p0.w);
      wv[2] = fmaxf(Eu*p1.x, Fu*p1.y); wv[3] = fmaxf(Eu*p1.z, Fu*p1.w);
      wv[4] = fmaxf(Eu*p2.x, Fu*p2.y); wv[5] = fmaxf(Eu*p2.z, Fu*p2.w);
      wv[6] = fmaxf(Eu*p3.x, Fu*p3.y); wv[7] = fmaxf(Eu*p3.z, Fu*p3.w);
      u32 bb = ((h ? mhi : mlo) >> (grp*8)) & 0xffu;
      union { u32 uu[4]; short8 v; } pk;
      #pragma unroll
      for (int p = 0; p < 4; ++p) {
        int j = 2*p;
        int slo = ((int)(bb << (31 - j))) >> 31;
        int shi = ((int)(bb << (30 - j))) >> 31;
        u32 msk = __builtin_amdgcn_perm((u32)shi, (u32)slo, 0x05040100u);
        u32 w01 = __builtin_amdgcn_perm(__float_as_uint(wv[j+1]),
                                        __float_as_uint(wv[j]), 0x07060302u);
        pk.uu[p] = w01 & msk;
      }
      af01[h] = pk.v;
    }
    const unsigned short* xb = XT2 + ((size_t)(k0 >> 5))*2048 + l*8;
    #pragma unroll
    for (int q = 0; q < 4; ++q) {
      short8 b0 = *(const short8*)(xb + q*512);
      short8 b1 = *(const short8*)(xb + 2048 + q*512);
      acc[q] = __builtin_amdgcn_mfma_f32_16x16x32_bf16(af01[0], b0, acc[q], 0, 0, 0);
      acc[q] = __builtin_amdgcn_mfma_f32_16x16x32_bf16(af01[1], b1, acc[q], 0, 0, 0);
    }
    accs = __builtin_amdgcn_mfma_f32_16x16x32_bf16(af01[0], bones, accs, 0, 0, 0);
    accs = __builtin_amdgcn_mfma_f32_16x16x32_bf16(af01[1], bones, accs, 0, 0, 0);
  }

  if (row16 == 0) {
    #pragma unroll
    for (int r = 0; r < 4; ++r)
      sumP[(size_t)split*NU + rb*64 + wave*16 + grp*4 + r] = accs[r];
  }
  float* ap = accP + (size_t)split*NU*NF;
  #pragma unroll
  for (int q = 0; q < 4; ++q) {
    #pragma unroll
    for (int r = 0; r < 4; ++r) {
      int uo = rb*64 + wave*16 + grp*4 + r;
      ap[(size_t)uo*NF + q*16 + row16] = acc[q][r];
    }
  }
}

__global__ __launch_bounds__(256, 4) void agg_fused(
    const u64* __restrict__ RBt,
    const float* __restrict__ EFs, const float* __restrict__ EFt,
    const unsigned short* __restrict__ XT2s, const unsigned short* __restrict__ XT2t,
    float* __restrict__ P0, float* __restrict__ S0,
    float* __restrict__ P1, float* __restrict__ S1)
{
  __shared__ u64 cbS[16*64];   // 8KB, DIR1 transpose staging
  int b = blockIdx.x;
  if (b < 64*SPL0) {
    agg_body<0>(b & 63, b >> 6, RBt, EFt, EFs, XT2s, P0, S0, cbS);
  } else {
    int b2 = b - 64*SPL0;
    agg_body<1>(b2 & 127, b2 >> 7, RBt, EFs, EFt, XT2t, P1, S1, cbS);
  }
}

// ---------------- K3: reduce partials + normalize + bias + elu, float4-vectorized
__global__ __launch_bounds__(256) void finalize_kernel(
    const float* __restrict__ P0, const float* __restrict__ S0,
    const float* __restrict__ P1, const float* __restrict__ S1,
    const float* __restrict__ bias_s, const float* __restrict__ bias_t,
    float* __restrict__ out)
{
  int tid = blockIdx.x*256 + threadIdx.x;   // one float4 per thread
  const int n0 = N_T*NF/4;
  float4 a = make_float4(0.f, 0.f, 0.f, 0.f);
  float den = 0.f;
  float4 bias;
  if (tid < n0) {
    int u = tid >> 4, fq = (tid & 15)*4;
    #pragma unroll
    for (int s = 0; s < SPL0; ++s) {
      float4 p = *(const float4*)&P0[((size_t)s*N_T + u)*NF + fq];
      a.x += p.x; a.y += p.y; a.z += p.z; a.w += p.w;
      den += S0[(size_t)s*N_T + u];
    }
    bias = *(const float4*)&bias_s[fq];
  } else {
    int i2 = tid - n0;
    int u = i2 >> 4, fq = (i2 & 15)*4;
    #pragma unroll
    for (int s = 0; s < SPL1; ++s) {
      float4 p = *(const float4*)&P1[((size_t)s*N_S + u)*NF + fq];
      a.x += p.x; a.y += p.y; a.z += p.z; a.w += p.w;
      den += S1[(size_t)s*N_S + u];
    }
    bias = *(const float4*)&bias_t[fq];
  }
  float inv = den > 0.f ? 1.f/den : 0.f;
  float4 v;
  v.x = a.x*inv + bias.x; v.y = a.y*inv + bias.y;
  v.z = a.z*inv + bias.z; v.w = a.w*inv + bias.w;
  v.x = v.x > 0.f ? v.x : expm1f(v.x);
  v.y = v.y > 0.f ? v.y : expm1f(v.y);
  v.z = v.z > 0.f ? v.z : expm1f(v.z);
  v.w = v.w > 0.f ? v.w : expm1f(v.w);
  *(float4*)&out[tid*4] = v;
}

extern "C" void kernel_launch(void* const* d_in, const int* in_sizes, int n_in,
                              void* d_out, int out_size, void* d_ws, size_t ws_size,
                              hipStream_t stream)
{
  const float* hs     = (const float*)d_in[0];
  const float* ht     = (const float*)d_in[1];
  const int*   A      = (const int*)  d_in[2];
  const float* Ws     = (const float*)d_in[3];
  const float* Wt     = (const float*)d_in[4];
  const float* a1     = (const float*)d_in[5];
  const float* bias_s = (const float*)d_in[6];
  const float* bias_t = (const float*)d_in[7];
  float* out = (float*)d_out;

  u64* RBt = (u64*)d_ws;                                     // 4MB
  unsigned short* XT2s = (unsigned short*)(RBt + (size_t)(N_S/64)*N_T); // 1MB
  unsigned short* XT2t = XT2s + (size_t)NF*N_S;              // 0.5MB
  float* EFs = (float*)(XT2t + (size_t)NF*N_T);              // 2*8192
  float* EFt = EFs + 2*N_S;                                  // 2*4096
  float* P0  = EFt + 2*N_T;                                  // SPL0*4096*64 = 8MB
  float* S0  = P0 + (size_t)SPL0*N_T*NF;                     // SPL0*4096
  float* P1  = S0 + (size_t)SPL0*N_T;                        // SPL1*8192*64 = 8MB
  float* S1  = P1 + (size_t)SPL1*N_S*NF;                     // SPL1*8192

  k1_fused<<<2048 + (N_S + N_T)/4, 256, 0, stream>>>(A, RBt, hs, ht, Ws, Wt, a1,
                                                     XT2s, XT2t, EFs, EFt);
  agg_fused<<<64*SPL0 + 128*SPL1, 256, 0, stream>>>(RBt, EFs, EFt, XT2s, XT2t,
                                                    P0, S0, P1, S1);
  finalize_kernel<<<(N_T*NF + N_S*NF)/1024, 256, 0, stream>>>(P0, S0, P1, S1,
                                                              bias_s, bias_t, out);
}

// Round 11
// 76.176 us; speedup vs baseline: 3.0633x; 1.1074x over previous
//
#include <hip/hip_runtime.h>
#include <math.h>

#define N_S 8192
#define N_T 4096
#define DIN 128
#define NF  64
#define SPL0 8
#define SPL1 4

typedef __attribute__((ext_vector_type(8))) short short8;
typedef __attribute__((ext_vector_type(4))) float f32x4;
typedef __attribute__((ext_vector_type(4))) int i32x4;
typedef __attribute__((ext_vector_type(4))) unsigned short us4;
typedef unsigned long long u64;
typedef unsigned int u32;

__device__ __forceinline__ unsigned short f2bf(float x){
  unsigned u = __float_as_uint(x);
  unsigned r = (u + 0x7fffu + ((u >> 16) & 1u)) >> 16;
  return (unsigned short)r;
}
__device__ __forceinline__ float bf2f(unsigned short s){
  return __uint_as_float(((unsigned)s) << 16);
}

// ---------------- K1: fused {stream-compact A -> RBt} + {proj via split-bf16 MFMA}
// Compact: block b owns rows {2b,2b+1} of A (64KB contiguous); wave streams 16KB.
// Proj: 192 blocks x 64 rows. acc = h@W via 3-term split-bf16 MFMA (err ~2^-17).
// No LDS in proj: A-frags from global (lines fully consumed), B-frags from L2-resident W.
__global__ __launch_bounds__(256) void k1_fused(
    const int* __restrict__ A,
    u64* __restrict__ RBt,       // [N_S/64][N_T]  bits of row i over j, chunk-major
    const float* __restrict__ hs, const float* __restrict__ ht,
    const float* __restrict__ Ws, const float* __restrict__ Wt,
    const float* __restrict__ a1,
    unsigned short* __restrict__ XT2s, unsigned short* __restrict__ XT2t,
    float* __restrict__ EFs, float* __restrict__ EFt)
{
  __shared__ u64 rbS[2*128];    // 2KB, compact blocks only
  int bx = blockIdx.x;
  int t = threadIdx.x;
  if (bx < 2048) {
    // ---- stream-compact rows 2bx, 2bx+1 ----
    int w = t >> 6, l = t & 63;
    int i = 2*bx + (w >> 1);
    int h = w & 1;
    const int* base = A + (size_t)i*N_S + h*4096;
    #pragma unroll
    for (int it = 0; it < 16; ++it) {
      i32x4 v = *(const i32x4*)(base + it*256 + 4*l);
      u32 nib = (v.x > 0 ? 1u : 0u) | (v.y > 0 ? 2u : 0u)
              | (v.z > 0 ? 4u : 0u) | (v.w > 0 ? 8u : 0u);
      u32 b8  = nib | (((u32)__shfl_xor((int)nib, 1, 64)) << 4);
      u32 b16 = b8  | (((u32)__shfl_xor((int)b8,  2, 64)) << 8);
      u32 b32 = b16 | (((u32)__shfl_xor((int)b16, 4, 64)) << 16);
      u32 hi  = (u32)__shfl_xor((int)b32, 8, 64);
      if ((l & 15) == 0)
        rbS[(size_t)(w>>1)*128 + h*64 + it*4 + (l>>4)] = (u64)b32 | ((u64)hi << 32);
    }
    __syncthreads();
    int wi = t >> 1, ri = t & 1;
    RBt[(size_t)wi*N_T + 2*bx + ri] = rbS[(size_t)ri*128 + wi];
  } else {
    // ---- proj-MFMA: 64 rows per block ----
    int b = bx - 2048;
    int w = t >> 6, l = t & 63, l15 = l & 15, grp = l >> 4;
    bool is_s = b < (N_S/64);
    const float* h; const float* W; const float* av;
    unsigned short* XT; float* EFd; int r0;
    if (is_s) { r0 = b*64;              h = hs; W = Ws; av = a1 + 64; XT = XT2s; EFd = EFs; }
    else      { r0 = (b - (N_S/64))*64; h = ht; W = Wt; av = a1;      XT = XT2t; EFd = EFt; }
    int rbase = r0 + w*16;
    // A-frags: h[rbase+l15][kq*32 + grp*8 + j], split hi/lo
    short8 ahi[4], alo[4];
    const float* hp0 = h + (size_t)(rbase + l15)*DIN + grp*8;
    #pragma unroll
    for (int kq = 0; kq < 4; ++kq) {
      float4 x0 = *(const float4*)(hp0 + kq*32);
      float4 x1 = *(const float4*)(hp0 + kq*32 + 4);
      float xs[8] = {x0.x,x0.y,x0.z,x0.w,x1.x,x1.y,x1.z,x1.w};
      #pragma unroll
      for (int j = 0; j < 8; ++j) {
        unsigned short hi = f2bf(xs[j]);
        float res = xs[j] - bf2f(hi);
        ahi[kq][j] = (short)hi; alo[kq][j] = (short)f2bf(res);
      }
    }
    float part[4] = {0.f, 0.f, 0.f, 0.f};
    #pragma unroll
    for (int fq = 0; fq < 4; ++fq) {
      f32x4 acc; acc[0]=0.f; acc[1]=0.f; acc[2]=0.f; acc[3]=0.f;
      #pragma unroll
      for (int kq = 0; kq < 4; ++kq) {
        short8 bhi, blo;
        #pragma unroll
        for (int j = 0; j < 8; ++j) {
          float x = W[(size_t)(kq*32 + grp*8 + j)*NF + fq*16 + l15];
          unsigned short hi = f2bf(x);
          float res = x - bf2f(hi);
          bhi[j] = (short)hi; blo[j] = (short)f2bf(res);
        }
        acc = __builtin_amdgcn_mfma_f32_16x16x32_bf16(ahi[kq], bhi, acc, 0, 0, 0);
        acc = __builtin_amdgcn_mfma_f32_16x16x32_bf16(ahi[kq], blo, acc, 0, 0, 0);
        acc = __builtin_amdgcn_mfma_f32_16x16x32_bf16(alo[kq], bhi, acc, 0, 0, 0);
      }
      // XT2 store: lane f = fq*16+l15 fixed, rows rbase+grp*4+{0..3} -> 8B bf16x4
      us4 st;
      #pragma unroll
      for (int r = 0; r < 4; ++r) st[r] = f2bf(acc[r]);
      size_t basee = (size_t)((r0 >> 5) + (w >> 1))*2048 + fq*512
                   + ((2*w + (grp >> 1)) & 3)*128 + l15*8 + (grp & 1)*4;
      *(us4*)&XT[basee] = st;
      float af = av[fq*16 + l15];
      #pragma unroll
      for (int r = 0; r < 4; ++r) part[r] += acc[r]*af;
    }
    // p[r] reduce over the 16-lane f-groups
    #pragma unroll
    for (int o = 1; o < 16; o <<= 1) {
      #pragma unroll
      for (int r = 0; r < 4; ++r) part[r] += __shfl_xor(part[r], o, 64);
    }
    if (l15 == 0) {
      #pragma unroll
      for (int r = 0; r < 4; ++r) {
        int rr = rbase + grp*4 + r;
        float p = part[r];
        EFd[2*rr]     = __expf(p);
        EFd[2*rr + 1] = __expf(0.1f*p);
      }
    }
  }
}

// ---------------- K2: fused both-direction masked aggregation via MFMA bf16.
// DIR0: mask word direct from RBt. DIR1: block prologue butterfly-transposes its
// needed 64x64 bit-tiles into LDS. w(u,k) = bit * max(Eu*Ek, Fu*Fk).
template<int DIR>
__device__ __forceinline__ void agg_body(
    int rb, int split,
    const u64* __restrict__ RBt,
    const float* __restrict__ EFu, const float* __restrict__ EFk,
    const unsigned short* __restrict__ XT2,
    float* __restrict__ accP,   // [SPL][NU][NF]
    float* __restrict__ sumP,   // [SPL][NU]
    u64* cbS)                   // LDS [16][64], DIR1 only
{
  constexpr int NK = (DIR == 0) ? N_S : N_T;
  constexpr int NU = (DIR == 0) ? N_T : N_S;
  constexpr int SPL = (DIR == 0) ? SPL0 : SPL1;
  constexpr int KCH = NK / SPL;
  int t = threadIdx.x;
  int wave = t >> 6, l = t & 63;
  int row16 = l & 15, grp = l >> 4;
  int u = rb*64 + wave*16 + row16;
  int kc0 = split * KCH;

  if (DIR == 1) {
    const u64 MM[6] = {0x00000000FFFFFFFFull, 0x0000FFFF0000FFFFull, 0x00FF00FF00FF00FFull,
                       0x0F0F0F0F0F0F0F0Full, 0x3333333333333333ull, 0x5555555555555555ull};
    const int DD[6] = {32, 16, 8, 4, 2, 1};
    #pragma unroll
    for (int cc = 0; cc < 4; ++cc) {
      int c = wave*4 + cc;
      u64 x = RBt[(size_t)rb*N_T + kc0 + c*64 + l];
      #pragma unroll
      for (int s = 0; s < 6; ++s) {
        int d = DD[s]; u64 M = MM[s];
        u32 ylo = (u32)__shfl_xor((int)(u32)x, d, 64);
        u32 yhi = (u32)__shfl_xor((int)(u32)(x >> 32), d, 64);
        u64 y = (u64)ylo | ((u64)yhi << 32);
        x = ((l & d) == 0) ? ((x & M) | ((y & M) << d))
                           : ((x & ~M) | ((y & ~M) >> d));
      }
      cbS[c*64 + l] = x;
    }
    __syncthreads();
  }

  float2 ef = *(const float2*)&EFu[2*u];
  float Eu = ef.x, Fu = ef.y;
  f32x4 acc[4];
  #pragma unroll
  for (int q = 0; q < 4; ++q) { acc[q][0]=0.f; acc[q][1]=0.f; acc[q][2]=0.f; acc[q][3]=0.f; }
  f32x4 accs; accs[0]=0.f; accs[1]=0.f; accs[2]=0.f; accs[3]=0.f;
  short8 bones;
  #pragma unroll
  for (int j = 0; j < 8; ++j) bones[j] = (short)0x3F80;   // bf16(1.0)

  #pragma unroll 2
  for (int k0 = kc0; k0 < kc0 + KCH; k0 += 64) {
    u64 mb = (DIR == 0) ? RBt[(size_t)(k0 >> 6)*NU + u]
                        : cbS[((k0 - kc0) >> 6)*64 + wave*16 + row16];
    u32 mlo = (u32)mb, mhi = (u32)(mb >> 32);
    short8 af01[2];
    #pragma unroll
    for (int h = 0; h < 2; ++h) {
      int kb = k0 + 32*h + grp*8;
      float4 p0 = *(const float4*)&EFk[2*kb];
      float4 p1 = *(const float4*)&EFk[2*kb + 4];
      float4 p2 = *(const float4*)&EFk[2*kb + 8];
      float4 p3 = *(const float4*)&EFk[2*kb + 12];
      float wv[8];
      wv[0] = fmaxf(Eu*p0.x, Fu*p0.y); wv[1] = fmaxf(Eu*p0.z, Fu*p0.w);
      wv[2] = fmaxf(Eu*p1.x, Fu*p1.y); wv[3] = fmaxf(Eu*p1.z, Fu*p1.w);
      wv[4] = fmaxf(Eu*p2.x, Fu*p2.y); wv[5] = fmaxf(Eu*p2.z, Fu*p2.w);
      wv[6] = fmaxf(Eu*p3.x, Fu*p3.y); wv[7] = fmaxf(Eu*p3.z, Fu*p3.w);
      u32 bb = ((h ? mhi : mlo) >> (grp*8)) & 0xffu;
      union { u32 uu[4]; short8 v; } pk;
      #pragma unroll
      for (int p = 0; p < 4; ++p) {
        int j = 2*p;
        int slo = ((int)(bb << (31 - j))) >> 31;
        int shi = ((int)(bb << (30 - j))) >> 31;
        u32 msk = __builtin_amdgcn_perm((u32)shi, (u32)slo, 0x05040100u);
        u32 w01 = __builtin_amdgcn_perm(__float_as_uint(wv[j+1]),
                                        __float_as_uint(wv[j]), 0x07060302u);
        pk.uu[p] = w01 & msk;
      }
      af01[h] = pk.v;
    }
    const unsigned short* xb = XT2 + ((size_t)(k0 >> 5))*2048 + l*8;
    #pragma unroll
    for (int q = 0; q < 4; ++q) {
      short8 b0 = *(const short8*)(xb + q*512);
      short8 b1 = *(const short8*)(xb + 2048 + q*512);
      acc[q] = __builtin_amdgcn_mfma_f32_16x16x32_bf16(af01[0], b0, acc[q], 0, 0, 0);
      acc[q] = __builtin_amdgcn_mfma_f32_16x16x32_bf16(af01[1], b1, acc[q], 0, 0, 0);
    }
    accs = __builtin_amdgcn_mfma_f32_16x16x32_bf16(af01[0], bones, accs, 0, 0, 0);
    accs = __builtin_amdgcn_mfma_f32_16x16x32_bf16(af01[1], bones, accs, 0, 0, 0);
  }

  if (row16 == 0) {
    #pragma unroll
    for (int r = 0; r < 4; ++r)
      sumP[(size_t)split*NU + rb*64 + wave*16 + grp*4 + r] = accs[r];
  }
  float* ap = accP + (size_t)split*NU*NF;
  #pragma unroll
  for (int q = 0; q < 4; ++q) {
    #pragma unroll
    for (int r = 0; r < 4; ++r) {
      int uo = rb*64 + wave*16 + grp*4 + r;
      ap[(size_t)uo*NF + q*16 + row16] = acc[q][r];
    }
  }
}

__global__ __launch_bounds__(256, 4) void agg_fused(
    const u64* __restrict__ RBt,
    const float* __restrict__ EFs, const float* __restrict__ EFt,
    const unsigned short* __restrict__ XT2s, const unsigned short* __restrict__ XT2t,
    float* __restrict__ P0, float* __restrict__ S0,
    float* __restrict__ P1, float* __restrict__ S1)
{
  __shared__ u64 cbS[16*64];   // 8KB, DIR1 transpose staging
  int b = blockIdx.x;
  if (b < 64*SPL0) {
    agg_body<0>(b & 63, b >> 6, RBt, EFt, EFs, XT2s, P0, S0, cbS);
  } else {
    int b2 = b - 64*SPL0;
    agg_body<1>(b2 & 127, b2 >> 7, RBt, EFs, EFt, XT2t, P1, S1, cbS);
  }
}

// ---------------- K3: reduce partials + normalize + bias + elu, float4-vectorized
__global__ __launch_bounds__(256) void finalize_kernel(
    const float* __restrict__ P0, const float* __restrict__ S0,
    const float* __restrict__ P1, const float* __restrict__ S1,
    const float* __restrict__ bias_s, const float* __restrict__ bias_t,
    float* __restrict__ out)
{
  int tid = blockIdx.x*256 + threadIdx.x;   // one float4 per thread
  const int n0 = N_T*NF/4;
  float4 a = make_float4(0.f, 0.f, 0.f, 0.f);
  float den = 0.f;
  float4 bias;
  if (tid < n0) {
    int u = tid >> 4, fq = (tid & 15)*4;
    #pragma unroll
    for (int s = 0; s < SPL0; ++s) {
      float4 p = *(const float4*)&P0[((size_t)s*N_T + u)*NF + fq];
      a.x += p.x; a.y += p.y; a.z += p.z; a.w += p.w;
      den += S0[(size_t)s*N_T + u];
    }
    bias = *(const float4*)&bias_s[fq];
  } else {
    int i2 = tid - n0;
    int u = i2 >> 4, fq = (i2 & 15)*4;
    #pragma unroll
    for (int s = 0; s < SPL1; ++s) {
      float4 p = *(const float4*)&P1[((size_t)s*N_S + u)*NF + fq];
      a.x += p.x; a.y += p.y; a.z += p.z; a.w += p.w;
      den += S1[(size_t)s*N_S + u];
    }
    bias = *(const float4*)&bias_t[fq];
  }
  float inv = den > 0.f ? 1.f/den : 0.f;
  float4 v;
  v.x = a.x*inv + bias.x; v.y = a.y*inv + bias.y;
  v.z = a.z*inv + bias.z; v.w = a.w*inv + bias.w;
  v.x = v.x > 0.f ? v.x : expm1f(v.x);
  v.y = v.y > 0.f ? v.y : expm1f(v.y);
  v.z = v.z > 0.f ? v.z : expm1f(v.z);
  v.w = v.w > 0.f ? v.w : expm1f(v.w);
  *(float4*)&out[tid*4] = v;
}

extern "C" void kernel_launch(void* const* d_in, const int* in_sizes, int n_in,
                              void* d_out, int out_size, void* d_ws, size_t ws_size,
                              hipStream_t stream)
{
  const float* hs     = (const float*)d_in[0];
  const float* ht     = (const float*)d_in[1];
  const int*   A      = (const int*)  d_in[2];
  const float* Ws     = (const float*)d_in[3];
  const float* Wt     = (const float*)d_in[4];
  const float* a1     = (const float*)d_in[5];
  const float* bias_s = (const float*)d_in[6];
  const float* bias_t = (const float*)d_in[7];
  float* out = (float*)d_out;

  u64* RBt = (u64*)d_ws;                                     // 4MB
  unsigned short* XT2s = (unsigned short*)(RBt + (size_t)(N_S/64)*N_T); // 1MB
  unsigned short* XT2t = XT2s + (size_t)NF*N_S;              // 0.5MB
  float* EFs = (float*)(XT2t + (size_t)NF*N_T);              // 2*8192
  float* EFt = EFs + 2*N_S;                                  // 2*4096
  float* P0  = EFt + 2*N_T;                                  // SPL0*4096*64 = 8MB
  float* S0  = P0 + (size_t)SPL0*N_T*NF;                     // SPL0*4096
  float* P1  = S0 + (size_t)SPL0*N_T;                        // SPL1*8192*64 = 8MB
  float* S1  = P1 + (size_t)SPL1*N_S*NF;                     // SPL1*8192

  k1_fused<<<2048 + (N_S + N_T)/64, 256, 0, stream>>>(A, RBt, hs, ht, Ws, Wt, a1,
                                                      XT2s, XT2t, EFs, EFt);
  agg_fused<<<64*SPL0 + 128*SPL1, 256, 0, stream>>>(RBt, EFs, EFt, XT2s, XT2t,
                                                    P0, S0, P1, S1);
  finalize_kernel<<<(N_T*NF + N_S*NF)/1024, 256, 0, stream>>>(P0, S0, P1, S1,
                                                              bias_s, bias_t, out);
}

// Round 12
// 74.981 us; speedup vs baseline: 3.1121x; 1.0159x over previous
//
#include <hip/hip_runtime.h>
#include <math.h>

#define N_S 8192
#define N_T 4096
#define DIN 128
#define NF  64
#define SPL0 8
#define SPL1 4

typedef __attribute__((ext_vector_type(8))) short short8;
typedef __attribute__((ext_vector_type(4))) float f32x4;
typedef __attribute__((ext_vector_type(4))) unsigned short us4;
typedef unsigned long long u64;
typedef unsigned int u32;

__device__ __forceinline__ unsigned short f2bf(float x){
  unsigned u = __float_as_uint(x);
  unsigned r = (u + 0x7fffu + ((u >> 16) & 1u)) >> 16;
  return (unsigned short)r;
}
__device__ __forceinline__ float bf2f(unsigned short s){
  return __uint_as_float(((unsigned)s) << 16);
}

// ---------------- K1: fused {stream-compact A -> RBt via __ballot} + {proj via split-bf16 MFMA}
// Compact: block b owns rows {2b,2b+1} (64KB contiguous). Lane l loads 4 dwords at
// strides {0,64,128,192}+l per 256-elem step; __ballot packs bits IN HARDWARE.
// No shuffles, no per-element VALU chain -> memory-bound streaming.
__global__ __launch_bounds__(256) void k1_fused(
    const int* __restrict__ A,
    u64* __restrict__ RBt,       // [N_S/64][N_T]  bits of row i over j, chunk-major
    const float* __restrict__ hs, const float* __restrict__ ht,
    const float* __restrict__ Ws, const float* __restrict__ Wt,
    const float* __restrict__ a1,
    unsigned short* __restrict__ XT2s, unsigned short* __restrict__ XT2t,
    float* __restrict__ EFs, float* __restrict__ EFt)
{
  __shared__ u64 rbS[2*128];    // 2KB staging, compact blocks only
  int bx = blockIdx.x;
  int t = threadIdx.x;
  if (bx < 2048) {
    // ---- stream-compact rows 2bx, 2bx+1 ----
    int w = t >> 6, l = t & 63;
    int i = 2*bx + (w >> 1);
    int h = w & 1;
    const int* base = A + (size_t)i*N_S + h*4096;
    #pragma unroll
    for (int it = 0; it < 16; ++it) {
      const int* p = base + it*256 + l;
      int w0 = p[0], w1 = p[64], w2 = p[128], w3 = p[192];
      u64 b0 = __ballot(w0 > 0);
      u64 b1 = __ballot(w1 > 0);
      u64 b2 = __ballot(w2 > 0);
      u64 b3 = __ballot(w3 > 0);
      if (l < 4) {
        u64 x = (l == 0) ? b0 : (l == 1) ? b1 : (l == 2) ? b2 : b3;
        rbS[(w>>1)*128 + h*64 + it*4 + l] = x;
      }
    }
    __syncthreads();
    int wi = t >> 1, ri = t & 1;
    RBt[(size_t)wi*N_T + 2*bx + ri] = rbS[(size_t)ri*128 + wi];
  } else {
    // ---- proj-MFMA: 64 rows per block, split-bf16 (err ~2^-17), no LDS ----
    int b = bx - 2048;
    int w = t >> 6, l = t & 63, l15 = l & 15, grp = l >> 4;
    bool is_s = b < (N_S/64);
    const float* h; const float* W; const float* av;
    unsigned short* XT; float* EFd; int r0;
    if (is_s) { r0 = b*64;              h = hs; W = Ws; av = a1 + 64; XT = XT2s; EFd = EFs; }
    else      { r0 = (b - (N_S/64))*64; h = ht; W = Wt; av = a1;      XT = XT2t; EFd = EFt; }
    int rbase = r0 + w*16;
    short8 ahi[4], alo[4];
    const float* hp0 = h + (size_t)(rbase + l15)*DIN + grp*8;
    #pragma unroll
    for (int kq = 0; kq < 4; ++kq) {
      float4 x0 = *(const float4*)(hp0 + kq*32);
      float4 x1 = *(const float4*)(hp0 + kq*32 + 4);
      float xs[8] = {x0.x,x0.y,x0.z,x0.w,x1.x,x1.y,x1.z,x1.w};
      #pragma unroll
      for (int j = 0; j < 8; ++j) {
        unsigned short hi = f2bf(xs[j]);
        float res = xs[j] - bf2f(hi);
        ahi[kq][j] = (short)hi; alo[kq][j] = (short)f2bf(res);
      }
    }
    float part[4] = {0.f, 0.f, 0.f, 0.f};
    #pragma unroll
    for (int fq = 0; fq < 4; ++fq) {
      f32x4 acc; acc[0]=0.f; acc[1]=0.f; acc[2]=0.f; acc[3]=0.f;
      #pragma unroll
      for (int kq = 0; kq < 4; ++kq) {
        short8 bhi, blo;
        #pragma unroll
        for (int j = 0; j < 8; ++j) {
          float x = W[(size_t)(kq*32 + grp*8 + j)*NF + fq*16 + l15];
          unsigned short hi = f2bf(x);
          float res = x - bf2f(hi);
          bhi[j] = (short)hi; blo[j] = (short)f2bf(res);
        }
        acc = __builtin_amdgcn_mfma_f32_16x16x32_bf16(ahi[kq], bhi, acc, 0, 0, 0);
        acc = __builtin_amdgcn_mfma_f32_16x16x32_bf16(ahi[kq], blo, acc, 0, 0, 0);
        acc = __builtin_amdgcn_mfma_f32_16x16x32_bf16(alo[kq], bhi, acc, 0, 0, 0);
      }
      us4 st;
      #pragma unroll
      for (int r = 0; r < 4; ++r) st[r] = f2bf(acc[r]);
      size_t basee = (size_t)((r0 >> 5) + (w >> 1))*2048 + fq*512
                   + ((2*w + (grp >> 1)) & 3)*128 + l15*8 + (grp & 1)*4;
      *(us4*)&XT[basee] = st;
      float af = av[fq*16 + l15];
      #pragma unroll
      for (int r = 0; r < 4; ++r) part[r] += acc[r]*af;
    }
    #pragma unroll
    for (int o = 1; o < 16; o <<= 1) {
      #pragma unroll
      for (int r = 0; r < 4; ++r) part[r] += __shfl_xor(part[r], o, 64);
    }
    if (l15 == 0) {
      #pragma unroll
      for (int r = 0; r < 4; ++r) {
        int rr = rbase + grp*4 + r;
        float p = part[r];
        EFd[2*rr]     = __expf(p);
        EFd[2*rr + 1] = __expf(0.1f*p);
      }
    }
  }
}

// ---------------- K2: fused both-direction masked aggregation via MFMA bf16.
// DIR0: mask word direct from RBt. DIR1: block prologue butterfly-transposes its
// needed 64x64 bit-tiles into LDS. w(u,k) = bit * max(Eu*Ek, Fu*Fk).
template<int DIR>
__device__ __forceinline__ void agg_body(
    int rb, int split,
    const u64* __restrict__ RBt,
    const float* __restrict__ EFu, const float* __restrict__ EFk,
    const unsigned short* __restrict__ XT2,
    float* __restrict__ accP,   // [SPL][NU][NF]
    float* __restrict__ sumP,   // [SPL][NU]
    u64* cbS)                   // LDS [16][64], DIR1 only
{
  constexpr int NK = (DIR == 0) ? N_S : N_T;
  constexpr int NU = (DIR == 0) ? N_T : N_S;
  constexpr int SPL = (DIR == 0) ? SPL0 : SPL1;
  constexpr int KCH = NK / SPL;
  int t = threadIdx.x;
  int wave = t >> 6, l = t & 63;
  int row16 = l & 15, grp = l >> 4;
  int u = rb*64 + wave*16 + row16;
  int kc0 = split * KCH;

  if (DIR == 1) {
    const u64 MM[6] = {0x00000000FFFFFFFFull, 0x0000FFFF0000FFFFull, 0x00FF00FF00FF00FFull,
                       0x0F0F0F0F0F0F0F0Full, 0x3333333333333333ull, 0x5555555555555555ull};
    const int DD[6] = {32, 16, 8, 4, 2, 1};
    #pragma unroll
    for (int cc = 0; cc < 4; ++cc) {
      int c = wave*4 + cc;
      u64 x = RBt[(size_t)rb*N_T + kc0 + c*64 + l];
      #pragma unroll
      for (int s = 0; s < 6; ++s) {
        int d = DD[s]; u64 M = MM[s];
        u32 ylo = (u32)__shfl_xor((int)(u32)x, d, 64);
        u32 yhi = (u32)__shfl_xor((int)(u32)(x >> 32), d, 64);
        u64 y = (u64)ylo | ((u64)yhi << 32);
        x = ((l & d) == 0) ? ((x & M) | ((y & M) << d))
                           : ((x & ~M) | ((y & ~M) >> d));
      }
      cbS[c*64 + l] = x;
    }
    __syncthreads();
  }

  float2 ef = *(const float2*)&EFu[2*u];
  float Eu = ef.x, Fu = ef.y;
  f32x4 acc[4];
  #pragma unroll
  for (int q = 0; q < 4; ++q) { acc[q][0]=0.f; acc[q][1]=0.f; acc[q][2]=0.f; acc[q][3]=0.f; }
  f32x4 accs; accs[0]=0.f; accs[1]=0.f; accs[2]=0.f; accs[3]=0.f;
  short8 bones;
  #pragma unroll
  for (int j = 0; j < 8; ++j) bones[j] = (short)0x3F80;   // bf16(1.0)

  #pragma unroll 2
  for (int k0 = kc0; k0 < kc0 + KCH; k0 += 64) {
    u64 mb = (DIR == 0) ? RBt[(size_t)(k0 >> 6)*NU + u]
                        : cbS[((k0 - kc0) >> 6)*64 + wave*16 + row16];
    u32 mlo = (u32)mb, mhi = (u32)(mb >> 32);
    short8 af01[2];
    #pragma unroll
    for (int h = 0; h < 2; ++h) {
      int kb = k0 + 32*h + grp*8;
      float4 p0 = *(const float4*)&EFk[2*kb];
      float4 p1 = *(const float4*)&EFk[2*kb + 4];
      float4 p2 = *(const float4*)&EFk[2*kb + 8];
      float4 p3 = *(const float4*)&EFk[2*kb + 12];
      float wv[8];
      wv[0] = fmaxf(Eu*p0.x, Fu*p0.y); wv[1] = fmaxf(Eu*p0.z, Fu*p0.w);
      wv[2] = fmaxf(Eu*p1.x, Fu*p1.y); wv[3] = fmaxf(Eu*p1.z, Fu*p1.w);
      wv[4] = fmaxf(Eu*p2.x, Fu*p2.y); wv[5] = fmaxf(Eu*p2.z, Fu*p2.w);
      wv[6] = fmaxf(Eu*p3.x, Fu*p3.y); wv[7] = fmaxf(Eu*p3.z, Fu*p3.w);
      u32 bb = ((h ? mhi : mlo) >> (grp*8)) & 0xffu;
      union { u32 uu[4]; short8 v; } pk;
      #pragma unroll
      for (int p = 0; p < 4; ++p) {
        int j = 2*p;
        int slo = ((int)(bb << (31 - j))) >> 31;
        int shi = ((int)(bb << (30 - j))) >> 31;
        u32 msk = __builtin_amdgcn_perm((u32)shi, (u32)slo, 0x05040100u);
        u32 w01 = __builtin_amdgcn_perm(__float_as_uint(wv[j+1]),
                                        __float_as_uint(wv[j]), 0x07060302u);
        pk.uu[p] = w01 & msk;
      }
      af01[h] = pk.v;
    }
    const unsigned short* xb = XT2 + ((size_t)(k0 >> 5))*2048 + l*8;
    #pragma unroll
    for (int q = 0; q < 4; ++q) {
      short8 b0 = *(const short8*)(xb + q*512);
      short8 b1 = *(const short8*)(xb + 2048 + q*512);
      acc[q] = __builtin_amdgcn_mfma_f32_16x16x32_bf16(af01[0], b0, acc[q], 0, 0, 0);
      acc[q] = __builtin_amdgcn_mfma_f32_16x16x32_bf16(af01[1], b1, acc[q], 0, 0, 0);
    }
    accs = __builtin_amdgcn_mfma_f32_16x16x32_bf16(af01[0], bones, accs, 0, 0, 0);
    accs = __builtin_amdgcn_mfma_f32_16x16x32_bf16(af01[1], bones, accs, 0, 0, 0);
  }

  if (row16 == 0) {
    #pragma unroll
    for (int r = 0; r < 4; ++r)
      sumP[(size_t)split*NU + rb*64 + wave*16 + grp*4 + r] = accs[r];
  }
  float* ap = accP + (size_t)split*NU*NF;
  #pragma unroll
  for (int q = 0; q < 4; ++q) {
    #pragma unroll
    for (int r = 0; r < 4; ++r) {
      int uo = rb*64 + wave*16 + grp*4 + r;
      ap[(size_t)uo*NF + q*16 + row16] = acc[q][r];
    }
  }
}

__global__ __launch_bounds__(256, 4) void agg_fused(
    const u64* __restrict__ RBt,
    const float* __restrict__ EFs, const float* __restrict__ EFt,
    const unsigned short* __restrict__ XT2s, const unsigned short* __restrict__ XT2t,
    float* __restrict__ P0, float* __restrict__ S0,
    float* __restrict__ P1, float* __restrict__ S1)
{
  __shared__ u64 cbS[16*64];   // 8KB, DIR1 transpose staging
  int b = blockIdx.x;
  if (b < 64*SPL0) {
    agg_body<0>(b & 63, b >> 6, RBt, EFt, EFs, XT2s, P0, S0, cbS);
  } else {
    int b2 = b - 64*SPL0;
    agg_body<1>(b2 & 127, b2 >> 7, RBt, EFs, EFt, XT2t, P1, S1, cbS);
  }
}

// ---------------- K3: reduce partials + normalize + bias + elu, float4-vectorized
__global__ __launch_bounds__(256) void finalize_kernel(
    const float* __restrict__ P0, const float* __restrict__ S0,
    const float* __restrict__ P1, const float* __restrict__ S1,
    const float* __restrict__ bias_s, const float* __restrict__ bias_t,
    float* __restrict__ out)
{
  int tid = blockIdx.x*256 + threadIdx.x;   // one float4 per thread
  const int n0 = N_T*NF/4;
  float4 a = make_float4(0.f, 0.f, 0.f, 0.f);
  float den = 0.f;
  float4 bias;
  if (tid < n0) {
    int u = tid >> 4, fq = (tid & 15)*4;
    #pragma unroll
    for (int s = 0; s < SPL0; ++s) {
      float4 p = *(const float4*)&P0[((size_t)s*N_T + u)*NF + fq];
      a.x += p.x; a.y += p.y; a.z += p.z; a.w += p.w;
      den += S0[(size_t)s*N_T + u];
    }
    bias = *(const float4*)&bias_s[fq];
  } else {
    int i2 = tid - n0;
    int u = i2 >> 4, fq = (i2 & 15)*4;
    #pragma unroll
    for (int s = 0; s < SPL1; ++s) {
      float4 p = *(const float4*)&P1[((size_t)s*N_S + u)*NF + fq];
      a.x += p.x; a.y += p.y; a.z += p.z; a.w += p.w;
      den += S1[(size_t)s*N_S + u];
    }
    bias = *(const float4*)&bias_t[fq];
  }
  float inv = den > 0.f ? 1.f/den : 0.f;
  float4 v;
  v.x = a.x*inv + bias.x; v.y = a.y*inv + bias.y;
  v.z = a.z*inv + bias.z; v.w = a.w*inv + bias.w;
  v.x = v.x > 0.f ? v.x : expm1f(v.x);
  v.y = v.y > 0.f ? v.y : expm1f(v.y);
  v.z = v.z > 0.f ? v.z : expm1f(v.z);
  v.w = v.w > 0.f ? v.w : expm1f(v.w);
  *(float4*)&out[tid*4] = v;
}

extern "C" void kernel_launch(void* const* d_in, const int* in_sizes, int n_in,
                              void* d_out, int out_size, void* d_ws, size_t ws_size,
                              hipStream_t stream)
{
  const float* hs     = (const float*)d_in[0];
  const float* ht     = (const float*)d_in[1];
  const int*   A      = (const int*)  d_in[2];
  const float* Ws     = (const float*)d_in[3];
  const float* Wt     = (const float*)d_in[4];
  const float* a1     = (const float*)d_in[5];
  const float* bias_s = (const float*)d_in[6];
  const float* bias_t = (const float*)d_in[7];
  float* out = (float*)d_out;

  u64* RBt = (u64*)d_ws;                                     // 4MB
  unsigned short* XT2s = (unsigned short*)(RBt + (size_t)(N_S/64)*N_T); // 1MB
  unsigned short* XT2t = XT2s + (size_t)NF*N_S;              // 0.5MB
  float* EFs = (float*)(XT2t + (size_t)NF*N_T);              // 2*8192
  float* EFt = EFs + 2*N_S;                                  // 2*4096
  float* P0  = EFt + 2*N_T;                                  // SPL0*4096*64 = 8MB
  float* S0  = P0 + (size_t)SPL0*N_T*NF;                     // SPL0*4096
  float* P1  = S0 + (size_t)SPL0*N_T;                        // SPL1*8192*64 = 8MB
  float* S1  = P1 + (size_t)SPL1*N_S*NF;                     // SPL1*8192

  k1_fused<<<2048 + (N_S + N_T)/64, 256, 0, stream>>>(A, RBt, hs, ht, Ws, Wt, a1,
                                                      XT2s, XT2t, EFs, EFt);
  agg_fused<<<64*SPL0 + 128*SPL1, 256, 0, stream>>>(RBt, EFs, EFt, XT2s, XT2t,
                                                    P0, S0, P1, S1);
  finalize_kernel<<<(N_T*NF + N_S*NF)/1024, 256, 0, stream>>>(P0, S0, P1, S1,
                                                              bias_s, bias_t, out);
}

// Round 13
// 74.303 us; speedup vs baseline: 3.1405x; 1.0091x over previous
//
#include <hip/hip_runtime.h>
#include <math.h>

#define N_S 8192
#define N_T 4096
#define DIN 128
#define NF  64
#define SPL0 8
#define SPL1 4
#define NPROJ ((N_S + N_T)/64)   // 192 proj blocks, placed FIRST in the grid

typedef __attribute__((ext_vector_type(8))) short short8;
typedef __attribute__((ext_vector_type(4))) float f32x4;
typedef __attribute__((ext_vector_type(4))) unsigned short us4;
typedef unsigned long long u64;
typedef unsigned int u32;

__device__ __forceinline__ unsigned short f2bf(float x){
  unsigned u = __float_as_uint(x);
  unsigned r = (u + 0x7fffu + ((u >> 16) & 1u)) >> 16;
  return (unsigned short)r;
}
__device__ __forceinline__ float bf2f(unsigned short s){
  return __uint_as_float(((unsigned)s) << 16);
}

// ---------------- K1: fused {proj via split-bf16 MFMA, blocks FIRST} + {stream-compact A}
// Proj: W staged+split ONCE per block into LDS as packed (hi<<16|lo), stride 65
// (conflict-free); MFMAs reordered 4-fq-interleaved (no serial acc chain).
// Compact: block owns rows {2c,2c+1} (64KB contiguous); __ballot packs bits in HW.
__global__ __launch_bounds__(256) void k1_fused(
    const int* __restrict__ A,
    u64* __restrict__ RBt,       // [N_S/64][N_T]  bits of row i over j, chunk-major
    const float* __restrict__ hs, const float* __restrict__ ht,
    const float* __restrict__ Ws, const float* __restrict__ Wt,
    const float* __restrict__ a1,
    unsigned short* __restrict__ XT2s, unsigned short* __restrict__ XT2t,
    float* __restrict__ EFs, float* __restrict__ EFt)
{
  __shared__ __align__(16) u32 smemU[DIN*65];   // 33280B: proj Wpk; compact aliases 2KB
  int bx = blockIdx.x;
  int t = threadIdx.x;
  if (bx < NPROJ) {
    // ---- proj-MFMA: 64 rows per block ----
    int w = t >> 6, l = t & 63, l15 = l & 15, grp = l >> 4;
    bool is_s = bx < (N_S/64);
    const float* h; const float* W; const float* av;
    unsigned short* XT; float* EFd; int r0;
    if (is_s) { r0 = bx*64;               h = hs; W = Ws; av = a1 + 64; XT = XT2s; EFd = EFs; }
    else      { r0 = (bx - (N_S/64))*64;  h = ht; W = Wt; av = a1;      XT = XT2t; EFd = EFt; }
    // stage + split W once (coalesced loads, packed hi/lo, padded stride 65)
    for (int e = t; e < DIN*NF; e += 256) {
      float x = W[e];
      unsigned short hi = f2bf(x);
      unsigned short lo = f2bf(x - bf2f(hi));
      smemU[(e >> 6)*65 + (e & 63)] = ((u32)hi << 16) | lo;
    }
    __syncthreads();
    int rbase = r0 + w*16;
    // A-frags from global, split hi/lo
    short8 ahi[4], alo[4];
    const float* hp0 = h + (size_t)(rbase + l15)*DIN + grp*8;
    #pragma unroll
    for (int kq = 0; kq < 4; ++kq) {
      float4 x0 = *(const float4*)(hp0 + kq*32);
      float4 x1 = *(const float4*)(hp0 + kq*32 + 4);
      float xs[8] = {x0.x,x0.y,x0.z,x0.w,x1.x,x1.y,x1.z,x1.w};
      #pragma unroll
      for (int j = 0; j < 8; ++j) {
        unsigned short hi = f2bf(xs[j]);
        float res = xs[j] - bf2f(hi);
        ahi[kq][j] = (short)hi; alo[kq][j] = (short)f2bf(res);
      }
    }
    f32x4 acc[4];
    #pragma unroll
    for (int q = 0; q < 4; ++q) { acc[q][0]=0.f; acc[q][1]=0.f; acc[q][2]=0.f; acc[q][3]=0.f; }
    #pragma unroll
    for (int kq = 0; kq < 4; ++kq) {
      short8 bhi[4], blo[4];
      #pragma unroll
      for (int fq = 0; fq < 4; ++fq) {
        #pragma unroll
        for (int j = 0; j < 8; ++j) {
          u32 pk = smemU[(kq*32 + grp*8 + j)*65 + fq*16 + l15];
          bhi[fq][j] = (short)(pk >> 16);
          blo[fq][j] = (short)(pk & 0xffffu);
        }
      }
      // 4-way independent accumulators: no serial MFMA chain
      #pragma unroll
      for (int fq = 0; fq < 4; ++fq)
        acc[fq] = __builtin_amdgcn_mfma_f32_16x16x32_bf16(ahi[kq], bhi[fq], acc[fq], 0, 0, 0);
      #pragma unroll
      for (int fq = 0; fq < 4; ++fq)
        acc[fq] = __builtin_amdgcn_mfma_f32_16x16x32_bf16(ahi[kq], blo[fq], acc[fq], 0, 0, 0);
      #pragma unroll
      for (int fq = 0; fq < 4; ++fq)
        acc[fq] = __builtin_amdgcn_mfma_f32_16x16x32_bf16(alo[kq], bhi[fq], acc[fq], 0, 0, 0);
    }
    float part[4] = {0.f, 0.f, 0.f, 0.f};
    #pragma unroll
    for (int fq = 0; fq < 4; ++fq) {
      us4 st;
      #pragma unroll
      for (int r = 0; r < 4; ++r) st[r] = f2bf(acc[fq][r]);
      size_t basee = (size_t)((r0 >> 5) + (w >> 1))*2048 + fq*512
                   + ((2*w + (grp >> 1)) & 3)*128 + l15*8 + (grp & 1)*4;
      *(us4*)&XT[basee] = st;
      float af = av[fq*16 + l15];
      #pragma unroll
      for (int r = 0; r < 4; ++r) part[r] += acc[fq][r]*af;
    }
    #pragma unroll
    for (int o = 1; o < 16; o <<= 1) {
      #pragma unroll
      for (int r = 0; r < 4; ++r) part[r] += __shfl_xor(part[r], o, 64);
    }
    if (l15 == 0) {
      #pragma unroll
      for (int r = 0; r < 4; ++r) {
        int rr = rbase + grp*4 + r;
        float p = part[r];
        EFd[2*rr]     = __expf(p);
        EFd[2*rr + 1] = __expf(0.1f*p);
      }
    }
  } else {
    // ---- stream-compact rows 2c, 2c+1 (c = bx - NPROJ) ----
    u64* rbS = (u64*)smemU;              // 2KB alias
    int c = bx - NPROJ;
    int w = t >> 6, l = t & 63;
    int i = 2*c + (w >> 1);
    int h = w & 1;
    const int* base = A + (size_t)i*N_S + h*4096;
    #pragma unroll
    for (int it = 0; it < 16; ++it) {
      const int* p = base + it*256 + l;
      int w0 = p[0], w1 = p[64], w2 = p[128], w3 = p[192];
      u64 b0 = __ballot(w0 > 0);
      u64 b1 = __ballot(w1 > 0);
      u64 b2 = __ballot(w2 > 0);
      u64 b3 = __ballot(w3 > 0);
      if (l < 4) {
        u64 x = (l == 0) ? b0 : (l == 1) ? b1 : (l == 2) ? b2 : b3;
        rbS[(w>>1)*128 + h*64 + it*4 + l] = x;
      }
    }
    __syncthreads();
    int wi = t >> 1, ri = t & 1;
    RBt[(size_t)wi*N_T + 2*c + ri] = rbS[(size_t)ri*128 + wi];
  }
}

// ---------------- K2: fused both-direction masked aggregation via MFMA bf16.
// DIR0: mask word direct from RBt. DIR1: block prologue butterfly-transposes its
// needed 64x64 bit-tiles into LDS. w(u,k) = bit * max(Eu*Ek, Fu*Fk).
template<int DIR>
__device__ __forceinline__ void agg_body(
    int rb, int split,
    const u64* __restrict__ RBt,
    const float* __restrict__ EFu, const float* __restrict__ EFk,
    const unsigned short* __restrict__ XT2,
    float* __restrict__ accP,   // [SPL][NU][NF]
    float* __restrict__ sumP,   // [SPL][NU]
    u64* cbS)                   // LDS [16][64], DIR1 only
{
  constexpr int NK = (DIR == 0) ? N_S : N_T;
  constexpr int NU = (DIR == 0) ? N_T : N_S;
  constexpr int SPL = (DIR == 0) ? SPL0 : SPL1;
  constexpr int KCH = NK / SPL;
  int t = threadIdx.x;
  int wave = t >> 6, l = t & 63;
  int row16 = l & 15, grp = l >> 4;
  int u = rb*64 + wave*16 + row16;
  int kc0 = split * KCH;

  if (DIR == 1) {
    const u64 MM[6] = {0x00000000FFFFFFFFull, 0x0000FFFF0000FFFFull, 0x00FF00FF00FF00FFull,
                       0x0F0F0F0F0F0F0F0Full, 0x3333333333333333ull, 0x5555555555555555ull};
    const int DD[6] = {32, 16, 8, 4, 2, 1};
    #pragma unroll
    for (int cc = 0; cc < 4; ++cc) {
      int c = wave*4 + cc;
      u64 x = RBt[(size_t)rb*N_T + kc0 + c*64 + l];
      #pragma unroll
      for (int s = 0; s < 6; ++s) {
        int d = DD[s]; u64 M = MM[s];
        u32 ylo = (u32)__shfl_xor((int)(u32)x, d, 64);
        u32 yhi = (u32)__shfl_xor((int)(u32)(x >> 32), d, 64);
        u64 y = (u64)ylo | ((u64)yhi << 32);
        x = ((l & d) == 0) ? ((x & M) | ((y & M) << d))
                           : ((x & ~M) | ((y & ~M) >> d));
      }
      cbS[c*64 + l] = x;
    }
    __syncthreads();
  }

  float2 ef = *(const float2*)&EFu[2*u];
  float Eu = ef.x, Fu = ef.y;
  f32x4 acc[4];
  #pragma unroll
  for (int q = 0; q < 4; ++q) { acc[q][0]=0.f; acc[q][1]=0.f; acc[q][2]=0.f; acc[q][3]=0.f; }
  f32x4 accs; accs[0]=0.f; accs[1]=0.f; accs[2]=0.f; accs[3]=0.f;
  short8 bones;
  #pragma unroll
  for (int j = 0; j < 8; ++j) bones[j] = (short)0x3F80;   // bf16(1.0)

  #pragma unroll 2
  for (int k0 = kc0; k0 < kc0 + KCH; k0 += 64) {
    u64 mb = (DIR == 0) ? RBt[(size_t)(k0 >> 6)*NU + u]
                        : cbS[((k0 - kc0) >> 6)*64 + wave*16 + row16];
    u32 mlo = (u32)mb, mhi = (u32)(mb >> 32);
    short8 af01[2];
    #pragma unroll
    for (int h = 0; h < 2; ++h) {
      int kb = k0 + 32*h + grp*8;
      float4 p0 = *(const float4*)&EFk[2*kb];
      float4 p1 = *(const float4*)&EFk[2*kb + 4];
      float4 p2 = *(const float4*)&EFk[2*kb + 8];
      float4 p3 = *(const float4*)&EFk[2*kb + 12];
      float wv[8];
      wv[0] = fmaxf(Eu*p0.x, Fu*p0.y); wv[1] = fmaxf(Eu*p0.z, Fu*p0.w);
      wv[2] = fmaxf(Eu*p1.x, Fu*p1.y); wv[3] = fmaxf(Eu*p1.z, Fu*p1.w);
      wv[4] = fmaxf(Eu*p2.x, Fu*p2.y); wv[5] = fmaxf(Eu*p2.z, Fu*p2.w);
      wv[6] = fmaxf(Eu*p3.x, Fu*p3.y); wv[7] = fmaxf(Eu*p3.z, Fu*p3.w);
      u32 bb = ((h ? mhi : mlo) >> (grp*8)) & 0xffu;
      union { u32 uu[4]; short8 v; } pk;
      #pragma unroll
      for (int p = 0; p < 4; ++p) {
        int j = 2*p;
        int slo = ((int)(bb << (31 - j))) >> 31;
        int shi = ((int)(bb << (30 - j))) >> 31;
        u32 msk = __builtin_amdgcn_perm((u32)shi, (u32)slo, 0x05040100u);
        u32 w01 = __builtin_amdgcn_perm(__float_as_uint(wv[j+1]),
                                        __float_as_uint(wv[j]), 0x07060302u);
        pk.uu[p] = w01 & msk;
      }
      af01[h] = pk.v;
    }
    const unsigned short* xb = XT2 + ((size_t)(k0 >> 5))*2048 + l*8;
    #pragma unroll
    for (int q = 0; q < 4; ++q) {
      short8 b0 = *(const short8*)(xb + q*512);
      short8 b1 = *(const short8*)(xb + 2048 + q*512);
      acc[q] = __builtin_amdgcn_mfma_f32_16x16x32_bf16(af01[0], b0, acc[q], 0, 0, 0);
      acc[q] = __builtin_amdgcn_mfma_f32_16x16x32_bf16(af01[1], b1, acc[q], 0, 0, 0);
    }
    accs = __builtin_amdgcn_mfma_f32_16x16x32_bf16(af01[0], bones, accs, 0, 0, 0);
    accs = __builtin_amdgcn_mfma_f32_16x16x32_bf16(af01[1], bones, accs, 0, 0, 0);
  }

  if (row16 == 0) {
    #pragma unroll
    for (int r = 0; r < 4; ++r)
      sumP[(size_t)split*NU + rb*64 + wave*16 + grp*4 + r] = accs[r];
  }
  float* ap = accP + (size_t)split*NU*NF;
  #pragma unroll
  for (int q = 0; q < 4; ++q) {
    #pragma unroll
    for (int r = 0; r < 4; ++r) {
      int uo = rb*64 + wave*16 + grp*4 + r;
      ap[(size_t)uo*NF + q*16 + row16] = acc[q][r];
    }
  }
}

__global__ __launch_bounds__(256, 4) void agg_fused(
    const u64* __restrict__ RBt,
    const float* __restrict__ EFs, const float* __restrict__ EFt,
    const unsigned short* __restrict__ XT2s, const unsigned short* __restrict__ XT2t,
    float* __restrict__ P0, float* __restrict__ S0,
    float* __restrict__ P1, float* __restrict__ S1)
{
  __shared__ u64 cbS[16*64];   // 8KB, DIR1 transpose staging
  int b = blockIdx.x;
  if (b < 64*SPL0) {
    agg_body<0>(b & 63, b >> 6, RBt, EFt, EFs, XT2s, P0, S0, cbS);
  } else {
    int b2 = b - 64*SPL0;
    agg_body<1>(b2 & 127, b2 >> 7, RBt, EFs, EFt, XT2t, P1, S1, cbS);
  }
}

// ---------------- K3: reduce partials + normalize + bias + elu, float4-vectorized
__global__ __launch_bounds__(256) void finalize_kernel(
    const float* __restrict__ P0, const float* __restrict__ S0,
    const float* __restrict__ P1, const float* __restrict__ S1,
    const float* __restrict__ bias_s, const float* __restrict__ bias_t,
    float* __restrict__ out)
{
  int tid = blockIdx.x*256 + threadIdx.x;   // one float4 per thread
  const int n0 = N_T*NF/4;
  float4 a = make_float4(0.f, 0.f, 0.f, 0.f);
  float den = 0.f;
  float4 bias;
  if (tid < n0) {
    int u = tid >> 4, fq = (tid & 15)*4;
    #pragma unroll
    for (int s = 0; s < SPL0; ++s) {
      float4 p = *(const float4*)&P0[((size_t)s*N_T + u)*NF + fq];
      a.x += p.x; a.y += p.y; a.z += p.z; a.w += p.w;
      den += S0[(size_t)s*N_T + u];
    }
    bias = *(const float4*)&bias_s[fq];
  } else {
    int i2 = tid - n0;
    int u = i2 >> 4, fq = (i2 & 15)*4;
    #pragma unroll
    for (int s = 0; s < SPL1; ++s) {
      float4 p = *(const float4*)&P1[((size_t)s*N_S + u)*NF + fq];
      a.x += p.x; a.y += p.y; a.z += p.z; a.w += p.w;
      den += S1[(size_t)s*N_S + u];
    }
    bias = *(const float4*)&bias_t[fq];
  }
  float inv = den > 0.f ? 1.f/den : 0.f;
  float4 v;
  v.x = a.x*inv + bias.x; v.y = a.y*inv + bias.y;
  v.z = a.z*inv + bias.z; v.w = a.w*inv + bias.w;
  v.x = v.x > 0.f ? v.x : expm1f(v.x);
  v.y = v.y > 0.f ? v.y : expm1f(v.y);
  v.z = v.z > 0.f ? v.z : expm1f(v.z);
  v.w = v.w > 0.f ? v.w : expm1f(v.w);
  *(float4*)&out[tid*4] = v;
}

extern "C" void kernel_launch(void* const* d_in, const int* in_sizes, int n_in,
                              void* d_out, int out_size, void* d_ws, size_t ws_size,
                              hipStream_t stream)
{
  const float* hs     = (const float*)d_in[0];
  const float* ht     = (const float*)d_in[1];
  const int*   A      = (const int*)  d_in[2];
  const float* Ws     = (const float*)d_in[3];
  const float* Wt     = (const float*)d_in[4];
  const float* a1     = (const float*)d_in[5];
  const float* bias_s = (const float*)d_in[6];
  const float* bias_t = (const float*)d_in[7];
  float* out = (float*)d_out;

  u64* RBt = (u64*)d_ws;                                     // 4MB
  unsigned short* XT2s = (unsigned short*)(RBt + (size_t)(N_S/64)*N_T); // 1MB
  unsigned short* XT2t = XT2s + (size_t)NF*N_S;              // 0.5MB
  float* EFs = (float*)(XT2t + (size_t)NF*N_T);              // 2*8192
  float* EFt = EFs + 2*N_S;                                  // 2*4096
  float* P0  = EFt + 2*N_T;                                  // SPL0*4096*64 = 8MB
  float* S0  = P0 + (size_t)SPL0*N_T*NF;                     // SPL0*4096
  float* P1  = S0 + (size_t)SPL0*N_T;                        // SPL1*8192*64 = 8MB
  float* S1  = P1 + (size_t)SPL1*N_S*NF;                     // SPL1*8192

  k1_fused<<<NPROJ + 2048, 256, 0, stream>>>(A, RBt, hs, ht, Ws, Wt, a1,
                                             XT2s, XT2t, EFs, EFt);
  agg_fused<<<64*SPL0 + 128*SPL1, 256, 0, stream>>>(RBt, EFs, EFt, XT2s, XT2t,
                                                    P0, S0, P1, S1);
  finalize_kernel<<<(N_T*NF + N_S*NF)/1024, 256, 0, stream>>>(P0, S0, P1, S1,
                                                              bias_s, bias_t, out);
}

// Round 14
// 73.643 us; speedup vs baseline: 3.1687x; 1.0090x over previous
//
#include <hip/hip_runtime.h>
#include <math.h>

#define N_S 8192
#define N_T 4096
#define DIN 128
#define NF  64
#define SPL0 8
#define SPL1 4
#define NPROJ ((N_S + N_T)/64)   // 192 proj blocks, FIRST in the grid

typedef __attribute__((ext_vector_type(8))) short short8;
typedef __attribute__((ext_vector_type(4))) float f32x4;
typedef __attribute__((ext_vector_type(4))) unsigned short us4;
typedef unsigned long long u64;
typedef unsigned int u32;

__device__ __forceinline__ unsigned short f2bf(float x){
  unsigned u = __float_as_uint(x);
  unsigned r = (u + 0x7fffu + ((u >> 16) & 1u)) >> 16;
  return (unsigned short)r;
}
__device__ __forceinline__ float bf2f(unsigned short s){
  return __uint_as_float(((unsigned)s) << 16);
}

// ---------------- K1: fused {proj via split-bf16 MFMA, no LDS, blocks FIRST}
//                 + {stream-compact A via __ballot, 2KB LDS only}
// Whole-kernel LDS = 2KB -> compact blocks reach ~7 blocks/CU (VGPR-limited at 68).
__global__ __launch_bounds__(256) void k1_fused(
    const int* __restrict__ A,
    u64* __restrict__ RBt,       // [N_S/64][N_T]  bits of row i over j, chunk-major
    const float* __restrict__ hs, const float* __restrict__ ht,
    const float* __restrict__ Ws, const float* __restrict__ Wt,
    const float* __restrict__ a1,
    unsigned short* __restrict__ XT2s, unsigned short* __restrict__ XT2t,
    float* __restrict__ EFs, float* __restrict__ EFt)
{
  __shared__ u64 rbS[2*128];    // 2KB staging, compact blocks only
  int bx = blockIdx.x;
  int t = threadIdx.x;
  if (bx < NPROJ) {
    // ---- proj-MFMA: 64 rows per block, split-bf16 (err ~2^-17), no LDS ----
    int w = t >> 6, l = t & 63, l15 = l & 15, grp = l >> 4;
    bool is_s = bx < (N_S/64);
    const float* h; const float* W; const float* av;
    unsigned short* XT; float* EFd; int r0;
    if (is_s) { r0 = bx*64;              h = hs; W = Ws; av = a1 + 64; XT = XT2s; EFd = EFs; }
    else      { r0 = (bx - (N_S/64))*64; h = ht; W = Wt; av = a1;      XT = XT2t; EFd = EFt; }
    int rbase = r0 + w*16;
    short8 ahi[4], alo[4];
    const float* hp0 = h + (size_t)(rbase + l15)*DIN + grp*8;
    #pragma unroll
    for (int kq = 0; kq < 4; ++kq) {
      float4 x0 = *(const float4*)(hp0 + kq*32);
      float4 x1 = *(const float4*)(hp0 + kq*32 + 4);
      float xs[8] = {x0.x,x0.y,x0.z,x0.w,x1.x,x1.y,x1.z,x1.w};
      #pragma unroll
      for (int j = 0; j < 8; ++j) {
        unsigned short hi = f2bf(xs[j]);
        float res = xs[j] - bf2f(hi);
        ahi[kq][j] = (short)hi; alo[kq][j] = (short)f2bf(res);
      }
    }
    float part[4] = {0.f, 0.f, 0.f, 0.f};
    #pragma unroll
    for (int fq = 0; fq < 4; ++fq) {
      f32x4 acc; acc[0]=0.f; acc[1]=0.f; acc[2]=0.f; acc[3]=0.f;
      #pragma unroll
      for (int kq = 0; kq < 4; ++kq) {
        short8 bhi, blo;
        #pragma unroll
        for (int j = 0; j < 8; ++j) {
          float x = W[(size_t)(kq*32 + grp*8 + j)*NF + fq*16 + l15];
          unsigned short hi = f2bf(x);
          float res = x - bf2f(hi);
          bhi[j] = (short)hi; blo[j] = (short)f2bf(res);
        }
        acc = __builtin_amdgcn_mfma_f32_16x16x32_bf16(ahi[kq], bhi, acc, 0, 0, 0);
        acc = __builtin_amdgcn_mfma_f32_16x16x32_bf16(ahi[kq], blo, acc, 0, 0, 0);
        acc = __builtin_amdgcn_mfma_f32_16x16x32_bf16(alo[kq], bhi, acc, 0, 0, 0);
      }
      us4 st;
      #pragma unroll
      for (int r = 0; r < 4; ++r) st[r] = f2bf(acc[r]);
      size_t basee = (size_t)((r0 >> 5) + (w >> 1))*2048 + fq*512
                   + ((2*w + (grp >> 1)) & 3)*128 + l15*8 + (grp & 1)*4;
      *(us4*)&XT[basee] = st;
      float af = av[fq*16 + l15];
      #pragma unroll
      for (int r = 0; r < 4; ++r) part[r] += acc[r]*af;
    }
    #pragma unroll
    for (int o = 1; o < 16; o <<= 1) {
      #pragma unroll
      for (int r = 0; r < 4; ++r) part[r] += __shfl_xor(part[r], o, 64);
    }
    if (l15 == 0) {
      #pragma unroll
      for (int r = 0; r < 4; ++r) {
        int rr = rbase + grp*4 + r;
        float p = part[r];
        EFd[2*rr]     = __expf(p);
        EFd[2*rr + 1] = __expf(0.1f*p);
      }
    }
  } else {
    // ---- stream-compact rows 2c, 2c+1 (c = bx - NPROJ); __ballot packs in HW ----
    int c = bx - NPROJ;
    int w = t >> 6, l = t & 63;
    int i = 2*c + (w >> 1);
    int h = w & 1;
    const int* base = A + (size_t)i*N_S + h*4096;
    #pragma unroll
    for (int it = 0; it < 16; ++it) {
      const int* p = base + it*256 + l;
      int w0 = p[0], w1 = p[64], w2 = p[128], w3 = p[192];
      u64 b0 = __ballot(w0 > 0);
      u64 b1 = __ballot(w1 > 0);
      u64 b2 = __ballot(w2 > 0);
      u64 b3 = __ballot(w3 > 0);
      if (l < 4) {
        u64 x = (l == 0) ? b0 : (l == 1) ? b1 : (l == 2) ? b2 : b3;
        rbS[(w>>1)*128 + h*64 + it*4 + l] = x;
      }
    }
    __syncthreads();
    int wi = t >> 1, ri = t & 1;
    RBt[(size_t)wi*N_T + 2*c + ri] = rbS[(size_t)ri*128 + wi];
  }
}

// ---------------- K2: fused both-direction masked aggregation via MFMA bf16.
// DIR0: mask word direct from RBt. DIR1: block prologue butterfly-transposes its
// needed 64x64 bit-tiles into LDS. w(u,k) = bit * max(Eu*Ek, Fu*Fk).
template<int DIR>
__device__ __forceinline__ void agg_body(
    int rb, int split,
    const u64* __restrict__ RBt,
    const float* __restrict__ EFu, const float* __restrict__ EFk,
    const unsigned short* __restrict__ XT2,
    float* __restrict__ accP,   // [SPL][NU][NF]
    float* __restrict__ sumP,   // [SPL][NU]
    u64* cbS)                   // LDS [16][64], DIR1 only
{
  constexpr int NK = (DIR == 0) ? N_S : N_T;
  constexpr int NU = (DIR == 0) ? N_T : N_S;
  constexpr int SPL = (DIR == 0) ? SPL0 : SPL1;
  constexpr int KCH = NK / SPL;
  int t = threadIdx.x;
  int wave = t >> 6, l = t & 63;
  int row16 = l & 15, grp = l >> 4;
  int u = rb*64 + wave*16 + row16;
  int kc0 = split * KCH;

  if (DIR == 1) {
    const u64 MM[6] = {0x00000000FFFFFFFFull, 0x0000FFFF0000FFFFull, 0x00FF00FF00FF00FFull,
                       0x0F0F0F0F0F0F0F0Full, 0x3333333333333333ull, 0x5555555555555555ull};
    const int DD[6] = {32, 16, 8, 4, 2, 1};
    #pragma unroll
    for (int cc = 0; cc < 4; ++cc) {
      int c = wave*4 + cc;
      u64 x = RBt[(size_t)rb*N_T + kc0 + c*64 + l];
      #pragma unroll
      for (int s = 0; s < 6; ++s) {
        int d = DD[s]; u64 M = MM[s];
        u32 ylo = (u32)__shfl_xor((int)(u32)x, d, 64);
        u32 yhi = (u32)__shfl_xor((int)(u32)(x >> 32), d, 64);
        u64 y = (u64)ylo | ((u64)yhi << 32);
        x = ((l & d) == 0) ? ((x & M) | ((y & M) << d))
                           : ((x & ~M) | ((y & ~M) >> d));
      }
      cbS[c*64 + l] = x;
    }
    __syncthreads();
  }

  float2 ef = *(const float2*)&EFu[2*u];
  float Eu = ef.x, Fu = ef.y;
  f32x4 acc[4];
  #pragma unroll
  for (int q = 0; q < 4; ++q) { acc[q][0]=0.f; acc[q][1]=0.f; acc[q][2]=0.f; acc[q][3]=0.f; }
  f32x4 accs; accs[0]=0.f; accs[1]=0.f; accs[2]=0.f; accs[3]=0.f;
  short8 bones;
  #pragma unroll
  for (int j = 0; j < 8; ++j) bones[j] = (short)0x3F80;   // bf16(1.0)

  #pragma unroll 2
  for (int k0 = kc0; k0 < kc0 + KCH; k0 += 64) {
    u64 mb = (DIR == 0) ? RBt[(size_t)(k0 >> 6)*NU + u]
                        : cbS[((k0 - kc0) >> 6)*64 + wave*16 + row16];
    u32 mlo = (u32)mb, mhi = (u32)(mb >> 32);
    short8 af01[2];
    #pragma unroll
    for (int h = 0; h < 2; ++h) {
      int kb = k0 + 32*h + grp*8;
      float4 p0 = *(const float4*)&EFk[2*kb];
      float4 p1 = *(const float4*)&EFk[2*kb + 4];
      float4 p2 = *(const float4*)&EFk[2*kb + 8];
      float4 p3 = *(const float4*)&EFk[2*kb + 12];
      float wv[8];
      wv[0] = fmaxf(Eu*p0.x, Fu*p0.y); wv[1] = fmaxf(Eu*p0.z, Fu*p0.w);
      wv[2] = fmaxf(Eu*p1.x, Fu*p1.y); wv[3] = fmaxf(Eu*p1.z, Fu*p1.w);
      wv[4] = fmaxf(Eu*p2.x, Fu*p2.y); wv[5] = fmaxf(Eu*p2.z, Fu*p2.w);
      wv[6] = fmaxf(Eu*p3.x, Fu*p3.y); wv[7] = fmaxf(Eu*p3.z, Fu*p3.w);
      u32 bb = ((h ? mhi : mlo) >> (grp*8)) & 0xffu;
      union { u32 uu[4]; short8 v; } pk;
      #pragma unroll
      for (int p = 0; p < 4; ++p) {
        int j = 2*p;
        int slo = ((int)(bb << (31 - j))) >> 31;
        int shi = ((int)(bb << (30 - j))) >> 31;
        u32 msk = __builtin_amdgcn_perm((u32)shi, (u32)slo, 0x05040100u);
        u32 w01 = __builtin_amdgcn_perm(__float_as_uint(wv[j+1]),
                                        __float_as_uint(wv[j]), 0x07060302u);
        pk.uu[p] = w01 & msk;
      }
      af01[h] = pk.v;
    }
    const unsigned short* xb = XT2 + ((size_t)(k0 >> 5))*2048 + l*8;
    #pragma unroll
    for (int q = 0; q < 4; ++q) {
      short8 b0 = *(const short8*)(xb + q*512);
      short8 b1 = *(const short8*)(xb + 2048 + q*512);
      acc[q] = __builtin_amdgcn_mfma_f32_16x16x32_bf16(af01[0], b0, acc[q], 0, 0, 0);
      acc[q] = __builtin_amdgcn_mfma_f32_16x16x32_bf16(af01[1], b1, acc[q], 0, 0, 0);
    }
    accs = __builtin_amdgcn_mfma_f32_16x16x32_bf16(af01[0], bones, accs, 0, 0, 0);
    accs = __builtin_amdgcn_mfma_f32_16x16x32_bf16(af01[1], bones, accs, 0, 0, 0);
  }

  if (row16 == 0) {
    #pragma unroll
    for (int r = 0; r < 4; ++r)
      sumP[(size_t)split*NU + rb*64 + wave*16 + grp*4 + r] = accs[r];
  }
  float* ap = accP + (size_t)split*NU*NF;
  #pragma unroll
  for (int q = 0; q < 4; ++q) {
    #pragma unroll
    for (int r = 0; r < 4; ++r) {
      int uo = rb*64 + wave*16 + grp*4 + r;
      ap[(size_t)uo*NF + q*16 + row16] = acc[q][r];
    }
  }
}

__global__ __launch_bounds__(256, 4) void agg_fused(
    const u64* __restrict__ RBt,
    const float* __restrict__ EFs, const float* __restrict__ EFt,
    const unsigned short* __restrict__ XT2s, const unsigned short* __restrict__ XT2t,
    float* __restrict__ P0, float* __restrict__ S0,
    float* __restrict__ P1, float* __restrict__ S1)
{
  __shared__ u64 cbS[16*64];   // 8KB, DIR1 transpose staging
  int b = blockIdx.x;
  if (b < 64*SPL0) {
    agg_body<0>(b & 63, b >> 6, RBt, EFt, EFs, XT2s, P0, S0, cbS);
  } else {
    int b2 = b - 64*SPL0;
    agg_body<1>(b2 & 127, b2 >> 7, RBt, EFs, EFt, XT2t, P1, S1, cbS);
  }
}

// ---------------- K3: reduce partials + normalize + bias + elu, float4-vectorized
__global__ __launch_bounds__(256) void finalize_kernel(
    const float* __restrict__ P0, const float* __restrict__ S0,
    const float* __restrict__ P1, const float* __restrict__ S1,
    const float* __restrict__ bias_s, const float* __restrict__ bias_t,
    float* __restrict__ out)
{
  int tid = blockIdx.x*256 + threadIdx.x;   // one float4 per thread
  const int n0 = N_T*NF/4;
  float4 a = make_float4(0.f, 0.f, 0.f, 0.f);
  float den = 0.f;
  float4 bias;
  if (tid < n0) {
    int u = tid >> 4, fq = (tid & 15)*4;
    #pragma unroll
    for (int s = 0; s < SPL0; ++s) {
      float4 p = *(const float4*)&P0[((size_t)s*N_T + u)*NF + fq];
      a.x += p.x; a.y += p.y; a.z += p.z; a.w += p.w;
      den += S0[(size_t)s*N_T + u];
    }
    bias = *(const float4*)&bias_s[fq];
  } else {
    int i2 = tid - n0;
    int u = i2 >> 4, fq = (i2 & 15)*4;
    #pragma unroll
    for (int s = 0; s < SPL1; ++s) {
      float4 p = *(const float4*)&P1[((size_t)s*N_S + u)*NF + fq];
      a.x += p.x; a.y += p.y; a.z += p.z; a.w += p.w;
      den += S1[(size_t)s*N_S + u];
    }
    bias = *(const float4*)&bias_t[fq];
  }
  float inv = den > 0.f ? 1.f/den : 0.f;
  float4 v;
  v.x = a.x*inv + bias.x; v.y = a.y*inv + bias.y;
  v.z = a.z*inv + bias.z; v.w = a.w*inv + bias.w;
  v.x = v.x > 0.f ? v.x : expm1f(v.x);
  v.y = v.y > 0.f ? v.y : expm1f(v.y);
  v.z = v.z > 0.f ? v.z : expm1f(v.z);
  v.w = v.w > 0.f ? v.w : expm1f(v.w);
  *(float4*)&out[tid*4] = v;
}

extern "C" void kernel_launch(void* const* d_in, const int* in_sizes, int n_in,
                              void* d_out, int out_size, void* d_ws, size_t ws_size,
                              hipStream_t stream)
{
  const float* hs     = (const float*)d_in[0];
  const float* ht     = (const float*)d_in[1];
  const int*   A      = (const int*)  d_in[2];
  const float* Ws     = (const float*)d_in[3];
  const float* Wt     = (const float*)d_in[4];
  const float* a1     = (const float*)d_in[5];
  const float* bias_s = (const float*)d_in[6];
  const float* bias_t = (const float*)d_in[7];
  float* out = (float*)d_out;

  u64* RBt = (u64*)d_ws;                                     // 4MB
  unsigned short* XT2s = (unsigned short*)(RBt + (size_t)(N_S/64)*N_T); // 1MB
  unsigned short* XT2t = XT2s + (size_t)NF*N_S;              // 0.5MB
  float* EFs = (float*)(XT2t + (size_t)NF*N_T);              // 2*8192
  float* EFt = EFs + 2*N_S;                                  // 2*4096
  float* P0  = EFt + 2*N_T;                                  // SPL0*4096*64 = 8MB
  float* S0  = P0 + (size_t)SPL0*N_T*NF;                     // SPL0*4096
  float* P1  = S0 + (size_t)SPL0*N_T;                        // SPL1*8192*64 = 8MB
  float* S1  = P1 + (size_t)SPL1*N_S*NF;                     // SPL1*8192

  k1_fused<<<NPROJ + 2048, 256, 0, stream>>>(A, RBt, hs, ht, Ws, Wt, a1,
                                             XT2s, XT2t, EFs, EFt);
  agg_fused<<<64*SPL0 + 128*SPL1, 256, 0, stream>>>(RBt, EFs, EFt, XT2s, XT2t,
                                                    P0, S0, P1, S1);
  finalize_kernel<<<(N_T*NF + N_S*NF)/1024, 256, 0, stream>>>(P0, S0, P1, S1,
                                                              bias_s, bias_t, out);
}

// Round 15
// 71.921 us; speedup vs baseline: 3.2446x; 1.0239x over previous
//
#include <hip/hip_runtime.h>
#include <math.h>

#define N_S 8192
#define N_T 4096
#define DIN 128
#define NF  64
#define SPL0 8
#define SPL1 4
#define NPROJ ((N_S + N_T)/64)   // 192 proj blocks, FIRST in the grid

typedef __attribute__((ext_vector_type(8))) short short8;
typedef __attribute__((ext_vector_type(4))) float f32x4;
typedef __attribute__((ext_vector_type(4))) unsigned short us4;
typedef unsigned long long u64;
typedef unsigned int u32;

__device__ __forceinline__ unsigned short f2bf(float x){
  unsigned u = __float_as_uint(x);
  unsigned r = (u + 0x7fffu + ((u >> 16) & 1u)) >> 16;
  return (unsigned short)r;
}
__device__ __forceinline__ float bf2f(unsigned short s){
  return __uint_as_float(((unsigned)s) << 16);
}

// ---------------- K1: fused {proj via split-bf16 MFMA, no LDS, blocks FIRST}
//                 + {stream-compact A via __ballot, 2KB LDS only}
// k1's A-read runs at the measured per-direction read ceiling (~3.2 TB/s, m13 copy/2).
__global__ __launch_bounds__(256) void k1_fused(
    const int* __restrict__ A,
    u64* __restrict__ RBt,       // [N_S/64][N_T]  bits of row i over j, chunk-major
    const float* __restrict__ hs, const float* __restrict__ ht,
    const float* __restrict__ Ws, const float* __restrict__ Wt,
    const float* __restrict__ a1,
    unsigned short* __restrict__ XT2s, unsigned short* __restrict__ XT2t,
    float* __restrict__ EFs, float* __restrict__ EFt)
{
  __shared__ u64 rbS[2*128];    // 2KB staging, compact blocks only
  int bx = blockIdx.x;
  int t = threadIdx.x;
  if (bx < NPROJ) {
    // ---- proj-MFMA: 64 rows per block, split-bf16 (err ~2^-17), no LDS ----
    int w = t >> 6, l = t & 63, l15 = l & 15, grp = l >> 4;
    bool is_s = bx < (N_S/64);
    const float* h; const float* W; const float* av;
    unsigned short* XT; float* EFd; int r0;
    if (is_s) { r0 = bx*64;              h = hs; W = Ws; av = a1 + 64; XT = XT2s; EFd = EFs; }
    else      { r0 = (bx - (N_S/64))*64; h = ht; W = Wt; av = a1;      XT = XT2t; EFd = EFt; }
    int rbase = r0 + w*16;
    short8 ahi[4], alo[4];
    const float* hp0 = h + (size_t)(rbase + l15)*DIN + grp*8;
    #pragma unroll
    for (int kq = 0; kq < 4; ++kq) {
      float4 x0 = *(const float4*)(hp0 + kq*32);
      float4 x1 = *(const float4*)(hp0 + kq*32 + 4);
      float xs[8] = {x0.x,x0.y,x0.z,x0.w,x1.x,x1.y,x1.z,x1.w};
      #pragma unroll
      for (int j = 0; j < 8; ++j) {
        unsigned short hi = f2bf(xs[j]);
        float res = xs[j] - bf2f(hi);
        ahi[kq][j] = (short)hi; alo[kq][j] = (short)f2bf(res);
      }
    }
    float part[4] = {0.f, 0.f, 0.f, 0.f};
    #pragma unroll
    for (int fq = 0; fq < 4; ++fq) {
      f32x4 acc; acc[0]=0.f; acc[1]=0.f; acc[2]=0.f; acc[3]=0.f;
      #pragma unroll
      for (int kq = 0; kq < 4; ++kq) {
        short8 bhi, blo;
        #pragma unroll
        for (int j = 0; j < 8; ++j) {
          float x = W[(size_t)(kq*32 + grp*8 + j)*NF + fq*16 + l15];
          unsigned short hi = f2bf(x);
          float res = x - bf2f(hi);
          bhi[j] = (short)hi; blo[j] = (short)f2bf(res);
        }
        acc = __builtin_amdgcn_mfma_f32_16x16x32_bf16(ahi[kq], bhi, acc, 0, 0, 0);
        acc = __builtin_amdgcn_mfma_f32_16x16x32_bf16(ahi[kq], blo, acc, 0, 0, 0);
        acc = __builtin_amdgcn_mfma_f32_16x16x32_bf16(alo[kq], bhi, acc, 0, 0, 0);
      }
      us4 st;
      #pragma unroll
      for (int r = 0; r < 4; ++r) st[r] = f2bf(acc[r]);
      size_t basee = (size_t)((r0 >> 5) + (w >> 1))*2048 + fq*512
                   + ((2*w + (grp >> 1)) & 3)*128 + l15*8 + (grp & 1)*4;
      *(us4*)&XT[basee] = st;
      float af = av[fq*16 + l15];
      #pragma unroll
      for (int r = 0; r < 4; ++r) part[r] += acc[r]*af;
    }
    #pragma unroll
    for (int o = 1; o < 16; o <<= 1) {
      #pragma unroll
      for (int r = 0; r < 4; ++r) part[r] += __shfl_xor(part[r], o, 64);
    }
    if (l15 == 0) {
      #pragma unroll
      for (int r = 0; r < 4; ++r) {
        int rr = rbase + grp*4 + r;
        float p = part[r];
        EFd[2*rr]     = __expf(p);
        EFd[2*rr + 1] = __expf(0.1f*p);
      }
    }
  } else {
    // ---- stream-compact rows 2c, 2c+1 (c = bx - NPROJ); __ballot packs in HW ----
    int c = bx - NPROJ;
    int w = t >> 6, l = t & 63;
    int i = 2*c + (w >> 1);
    int h = w & 1;
    const int* base = A + (size_t)i*N_S + h*4096;
    #pragma unroll
    for (int it = 0; it < 16; ++it) {
      const int* p = base + it*256 + l;
      int w0 = p[0], w1 = p[64], w2 = p[128], w3 = p[192];
      u64 b0 = __ballot(w0 > 0);
      u64 b1 = __ballot(w1 > 0);
      u64 b2 = __ballot(w2 > 0);
      u64 b3 = __ballot(w3 > 0);
      if (l < 4) {
        u64 x = (l == 0) ? b0 : (l == 1) ? b1 : (l == 2) ? b2 : b3;
        rbS[(w>>1)*128 + h*64 + it*4 + l] = x;
      }
    }
    __syncthreads();
    int wi = t >> 1, ri = t & 1;
    RBt[(size_t)wi*N_T + 2*c + ri] = rbS[(size_t)ri*128 + wi];
  }
}

// ---------------- K2: fused both-direction masked aggregation via MFMA bf16.
// DIR0: mask word direct from RBt. DIR1: block prologue butterfly-transposes its
// needed 64x64 bit-tiles into LDS. w(u,k) = bit * max(Eu*Ek, Fu*Ff).
// Partials stored as bf16 (halves the P round-trip); denominators stay f32.
template<int DIR>
__device__ __forceinline__ void agg_body(
    int rb, int split,
    const u64* __restrict__ RBt,
    const float* __restrict__ EFu, const float* __restrict__ EFk,
    const unsigned short* __restrict__ XT2,
    unsigned short* __restrict__ accP,   // [SPL][NU][NF] bf16
    float* __restrict__ sumP,            // [SPL][NU] f32
    u64* cbS)                            // LDS [16][64], DIR1 only
{
  constexpr int NK = (DIR == 0) ? N_S : N_T;
  constexpr int NU = (DIR == 0) ? N_T : N_S;
  constexpr int SPL = (DIR == 0) ? SPL0 : SPL1;
  constexpr int KCH = NK / SPL;
  int t = threadIdx.x;
  int wave = t >> 6, l = t & 63;
  int row16 = l & 15, grp = l >> 4;
  int u = rb*64 + wave*16 + row16;
  int kc0 = split * KCH;

  if (DIR == 1) {
    const u64 MM[6] = {0x00000000FFFFFFFFull, 0x0000FFFF0000FFFFull, 0x00FF00FF00FF00FFull,
                       0x0F0F0F0F0F0F0F0Full, 0x3333333333333333ull, 0x5555555555555555ull};
    const int DD[6] = {32, 16, 8, 4, 2, 1};
    #pragma unroll
    for (int cc = 0; cc < 4; ++cc) {
      int c = wave*4 + cc;
      u64 x = RBt[(size_t)rb*N_T + kc0 + c*64 + l];
      #pragma unroll
      for (int s = 0; s < 6; ++s) {
        int d = DD[s]; u64 M = MM[s];
        u32 ylo = (u32)__shfl_xor((int)(u32)x, d, 64);
        u32 yhi = (u32)__shfl_xor((int)(u32)(x >> 32), d, 64);
        u64 y = (u64)ylo | ((u64)yhi << 32);
        x = ((l & d) == 0) ? ((x & M) | ((y & M) << d))
                           : ((x & ~M) | ((y & ~M) >> d));
      }
      cbS[c*64 + l] = x;
    }
    __syncthreads();
  }

  float2 ef = *(const float2*)&EFu[2*u];
  float Eu = ef.x, Fu = ef.y;
  f32x4 acc[4];
  #pragma unroll
  for (int q = 0; q < 4; ++q) { acc[q][0]=0.f; acc[q][1]=0.f; acc[q][2]=0.f; acc[q][3]=0.f; }
  f32x4 accs; accs[0]=0.f; accs[1]=0.f; accs[2]=0.f; accs[3]=0.f;
  short8 bones;
  #pragma unroll
  for (int j = 0; j < 8; ++j) bones[j] = (short)0x3F80;   // bf16(1.0)

  #pragma unroll 2
  for (int k0 = kc0; k0 < kc0 + KCH; k0 += 64) {
    u64 mb = (DIR == 0) ? RBt[(size_t)(k0 >> 6)*NU + u]
                        : cbS[((k0 - kc0) >> 6)*64 + wave*16 + row16];
    u32 mlo = (u32)mb, mhi = (u32)(mb >> 32);
    short8 af01[2];
    #pragma unroll
    for (int h = 0; h < 2; ++h) {
      int kb = k0 + 32*h + grp*8;
      float4 p0 = *(const float4*)&EFk[2*kb];
      float4 p1 = *(const float4*)&EFk[2*kb + 4];
      float4 p2 = *(const float4*)&EFk[2*kb + 8];
      float4 p3 = *(const float4*)&EFk[2*kb + 12];
      float wv[8];
      wv[0] = fmaxf(Eu*p0.x, Fu*p0.y); wv[1] = fmaxf(Eu*p0.z, Fu*p0.w);
      wv[2] = fmaxf(Eu*p1.x, Fu*p1.y); wv[3] = fmaxf(Eu*p1.z, Fu*p1.w);
      wv[4] = fmaxf(Eu*p2.x, Fu*p2.y); wv[5] = fmaxf(Eu*p2.z, Fu*p2.w);
      wv[6] = fmaxf(Eu*p3.x, Fu*p3.y); wv[7] = fmaxf(Eu*p3.z, Fu*p3.w);
      u32 bb = ((h ? mhi : mlo) >> (grp*8)) & 0xffu;
      union { u32 uu[4]; short8 v; } pk;
      #pragma unroll
      for (int p = 0; p < 4; ++p) {
        int j = 2*p;
        int slo = ((int)(bb << (31 - j))) >> 31;
        int shi = ((int)(bb << (30 - j))) >> 31;
        u32 msk = __builtin_amdgcn_perm((u32)shi, (u32)slo, 0x05040100u);
        u32 w01 = __builtin_amdgcn_perm(__float_as_uint(wv[j+1]),
                                        __float_as_uint(wv[j]), 0x07060302u);
        pk.uu[p] = w01 & msk;
      }
      af01[h] = pk.v;
    }
    const unsigned short* xb = XT2 + ((size_t)(k0 >> 5))*2048 + l*8;
    #pragma unroll
    for (int q = 0; q < 4; ++q) {
      short8 b0 = *(const short8*)(xb + q*512);
      short8 b1 = *(const short8*)(xb + 2048 + q*512);
      acc[q] = __builtin_amdgcn_mfma_f32_16x16x32_bf16(af01[0], b0, acc[q], 0, 0, 0);
      acc[q] = __builtin_amdgcn_mfma_f32_16x16x32_bf16(af01[1], b1, acc[q], 0, 0, 0);
    }
    accs = __builtin_amdgcn_mfma_f32_16x16x32_bf16(af01[0], bones, accs, 0, 0, 0);
    accs = __builtin_amdgcn_mfma_f32_16x16x32_bf16(af01[1], bones, accs, 0, 0, 0);
  }

  if (row16 == 0) {
    #pragma unroll
    for (int r = 0; r < 4; ++r)
      sumP[(size_t)split*NU + rb*64 + wave*16 + grp*4 + r] = accs[r];
  }
  unsigned short* ap = accP + (size_t)split*NU*NF;
  #pragma unroll
  for (int q = 0; q < 4; ++q) {
    #pragma unroll
    for (int r = 0; r < 4; ++r) {
      int uo = rb*64 + wave*16 + grp*4 + r;
      ap[(size_t)uo*NF + q*16 + row16] = f2bf(acc[q][r]);
    }
  }
}

__global__ __launch_bounds__(256, 4) void agg_fused(
    const u64* __restrict__ RBt,
    const float* __restrict__ EFs, const float* __restrict__ EFt,
    const unsigned short* __restrict__ XT2s, const unsigned short* __restrict__ XT2t,
    unsigned short* __restrict__ P0, float* __restrict__ S0,
    unsigned short* __restrict__ P1, float* __restrict__ S1)
{
  __shared__ u64 cbS[16*64];   // 8KB, DIR1 transpose staging
  int b = blockIdx.x;
  if (b < 64*SPL0) {
    agg_body<0>(b & 63, b >> 6, RBt, EFt, EFs, XT2s, P0, S0, cbS);
  } else {
    int b2 = b - 64*SPL0;
    agg_body<1>(b2 & 127, b2 >> 7, RBt, EFs, EFt, XT2t, P1, S1, cbS);
  }
}

// ---------------- K3: reduce bf16 partials + normalize + bias + elu
__global__ __launch_bounds__(256) void finalize_kernel(
    const unsigned short* __restrict__ P0, const float* __restrict__ S0,
    const unsigned short* __restrict__ P1, const float* __restrict__ S1,
    const float* __restrict__ bias_s, const float* __restrict__ bias_t,
    float* __restrict__ out)
{
  int tid = blockIdx.x*256 + threadIdx.x;   // one float4 (4 features) per thread
  const int n0 = N_T*NF/4;
  float4 a = make_float4(0.f, 0.f, 0.f, 0.f);
  float den = 0.f;
  float4 bias;
  if (tid < n0) {
    int u = tid >> 4, fq = (tid & 15)*4;
    #pragma unroll
    for (int s = 0; s < SPL0; ++s) {
      us4 p = *(const us4*)&P0[((size_t)s*N_T + u)*NF + fq];
      a.x += bf2f(p[0]); a.y += bf2f(p[1]); a.z += bf2f(p[2]); a.w += bf2f(p[3]);
      den += S0[(size_t)s*N_T + u];
    }
    bias = *(const float4*)&bias_s[fq];
  } else {
    int i2 = tid - n0;
    int u = i2 >> 4, fq = (i2 & 15)*4;
    #pragma unroll
    for (int s = 0; s < SPL1; ++s) {
      us4 p = *(const us4*)&P1[((size_t)s*N_S + u)*NF + fq];
      a.x += bf2f(p[0]); a.y += bf2f(p[1]); a.z += bf2f(p[2]); a.w += bf2f(p[3]);
      den += S1[(size_t)s*N_S + u];
    }
    bias = *(const float4*)&bias_t[fq];
  }
  float inv = den > 0.f ? 1.f/den : 0.f;
  float4 v;
  v.x = a.x*inv + bias.x; v.y = a.y*inv + bias.y;
  v.z = a.z*inv + bias.z; v.w = a.w*inv + bias.w;
  v.x = v.x > 0.f ? v.x : expm1f(v.x);
  v.y = v.y > 0.f ? v.y : expm1f(v.y);
  v.z = v.z > 0.f ? v.z : expm1f(v.z);
  v.w = v.w > 0.f ? v.w : expm1f(v.w);
  *(float4*)&out[tid*4] = v;
}

extern "C" void kernel_launch(void* const* d_in, const int* in_sizes, int n_in,
                              void* d_out, int out_size, void* d_ws, size_t ws_size,
                              hipStream_t stream)
{
  const float* hs     = (const float*)d_in[0];
  const float* ht     = (const float*)d_in[1];
  const int*   A      = (const int*)  d_in[2];
  const float* Ws     = (const float*)d_in[3];
  const float* Wt     = (const float*)d_in[4];
  const float* a1     = (const float*)d_in[5];
  const float* bias_s = (const float*)d_in[6];
  const float* bias_t = (const float*)d_in[7];
  float* out = (float*)d_out;

  u64* RBt = (u64*)d_ws;                                     // 4MB
  unsigned short* XT2s = (unsigned short*)(RBt + (size_t)(N_S/64)*N_T); // 1MB
  unsigned short* XT2t = XT2s + (size_t)NF*N_S;              // 0.5MB
  float* EFs = (float*)(XT2t + (size_t)NF*N_T);              // 2*8192
  float* EFt = EFs + 2*N_S;                                  // 2*4096
  unsigned short* P0 = (unsigned short*)(EFt + 2*N_T);       // SPL0*4096*64 bf16 = 4MB
  unsigned short* P1 = P0 + (size_t)SPL0*N_T*NF;             // SPL1*8192*64 bf16 = 4MB
  float* S0 = (float*)(P1 + (size_t)SPL1*N_S*NF);            // SPL0*4096
  float* S1 = S0 + (size_t)SPL0*N_T;                         // SPL1*8192

  k1_fused<<<NPROJ + 2048, 256, 0, stream>>>(A, RBt, hs, ht, Ws, Wt, a1,
                                             XT2s, XT2t, EFs, EFt);
  agg_fused<<<64*SPL0 + 128*SPL1, 256, 0, stream>>>(RBt, EFs, EFt, XT2s, XT2t,
                                                    P0, S0, P1, S1);
  finalize_kernel<<<(N_T*NF + N_S*NF)/1024, 256, 0, stream>>>(P0, S0, P1, S1,
                                                              bias_s, bias_t, out);
}